// Round 18
// baseline (383.779 us; speedup 1.0000x reference)
//
#include <hip/hip_runtime.h>
#include <hip/hip_bf16.h>
#include <math.h>

#define N_NODES  50000
#define N_EDGES  800000
#define E_TOT    850000   // + self loops
#define N_GRAPHS 512
#define IN_CH    58
#define K1P      64       // padded K for layer-1 MFMA
#define C1       256      // HEADS1 * H = 4*64
#define H1       4
#define C2       128
#define NEG_SLOPE 0.2f
#define SLOT_CAP 64       // fixed bucket capacity; P(Poisson(17) > 63) < 1e-13
#define NHIST    3321     // ceil(850000/256)
#define NATT     12500    // ceil(50000/4)

typedef __attribute__((ext_vector_type(8))) short short8;
typedef __attribute__((ext_vector_type(4))) float f32x4;

__device__ __forceinline__ float lo16(unsigned u) { return __uint_as_float(u << 16); }
__device__ __forceinline__ float hi16(unsigned u) { return __uint_as_float(u & 0xffff0000u); }
__device__ __forceinline__ float leaky(float e) { return e > 0.f ? e : NEG_SLOPE * e; }
__device__ __forceinline__ unsigned short f2bfu(float v) {
    __hip_bfloat16 b = __float2bfloat16(v);
    return *(unsigned short*)&b;
}
__device__ __forceinline__ unsigned pack2(float lo, float hi) {
    return (unsigned)f2bfu(lo) | ((unsigned)f2bfu(hi) << 16);
}

// ---- frontA: weight prep + att projections + single-pass bucket build (hist+scatter)
__global__ __launch_bounds__(256) void k_frontA(const float* __restrict__ W1,
                                                const float* __restrict__ W2,
                                                const float* __restrict__ atts1,
                                                const float* __restrict__ attd1,
                                                const int* __restrict__ src,
                                                const int* __restrict__ dst,
                                                unsigned short* __restrict__ w1p,
                                                unsigned short* __restrict__ w2p,
                                                float* __restrict__ wproj,
                                                int* __restrict__ deg,
                                                int* __restrict__ slots) {
    int b = blockIdx.x;
    int t = threadIdx.x;
    if (b < 256) {                     // w1p[c][k] = bf16(W1[k][c]), zero-pad k>=58
        if (t < K1P) {
            float v = (t < IN_CH) ? W1[t * C1 + b] : 0.f;
            w1p[b * K1P + t] = f2bfu(v);
        }
    } else if (b < 384) {              // w2p[n][k] = bf16(W2[k][n])
        int n = b - 256;
        w2p[n * C1 + t] = f2bfu(W2[t * C2 + n]);
    } else if (b < 385) {              // att projections through W1
        int k = t >> 2, h = t & 3;
        float s = 0.f, dd = 0.f;
        if (k < IN_CH) {
            for (int j = 0; j < 64; ++j) {
                float wv = W1[k * C1 + h * 64 + j];
                s  += wv * atts1[h * 64 + j];
                dd += wv * attd1[h * 64 + j];
            }
        }
        wproj[t] = s;
        wproj[256 + t] = dd;
    } else {                           // fused histogram + scatter into fixed buckets
        int j = (b - 385) * 256 + t;
        if (j < E_TOT) {
            int s, d;
            if (j < N_EDGES) { s = src[j]; d = dst[j]; } else { s = d = j - N_EDGES; }
            int pos = atomicAdd(&deg[d], 1);
            slots[(d << 6) + pos] = s;
        }
    }
}

// ---- frontB: layer-1 logits + x->bf16 cast + graph node counts ----
__global__ __launch_bounds__(256) void k_frontB(const float* __restrict__ x,
                                                const float* __restrict__ wproj,
                                                const int* __restrict__ batch,
                                                unsigned short* __restrict__ xbf,
                                                float* __restrict__ a_s,
                                                float* __restrict__ a_d,
                                                float* __restrict__ cnt) {
    int n = blockIdx.x * 4 + (threadIdx.x >> 6);
    int lane = threadIdx.x & 63;
    float xv = (lane < IN_CH) ? x[n * IN_CH + lane] : 0.f;
    xbf[n * K1P + lane] = f2bfu(xv);
    float ps0 = xv * wproj[lane * 4 + 0], ps1 = xv * wproj[lane * 4 + 1];
    float ps2 = xv * wproj[lane * 4 + 2], ps3 = xv * wproj[lane * 4 + 3];
    float pd0 = xv * wproj[256 + lane * 4 + 0], pd1 = xv * wproj[256 + lane * 4 + 1];
    float pd2 = xv * wproj[256 + lane * 4 + 2], pd3 = xv * wproj[256 + lane * 4 + 3];
#pragma unroll
    for (int o = 32; o > 0; o >>= 1) {
        ps0 += __shfl_down(ps0, o, 64); ps1 += __shfl_down(ps1, o, 64);
        ps2 += __shfl_down(ps2, o, 64); ps3 += __shfl_down(ps3, o, 64);
        pd0 += __shfl_down(pd0, o, 64); pd1 += __shfl_down(pd1, o, 64);
        pd2 += __shfl_down(pd2, o, 64); pd3 += __shfl_down(pd3, o, 64);
    }
    if (lane == 0) {
        *(float4*)(a_s + n * 4) = make_float4(ps0, ps1, ps2, ps3);
        *(float4*)(a_d + n * 4) = make_float4(pd0, pd1, pd2, pd3);
        atomicAdd(&cnt[batch[n]], 1.0f);
    }
}

// ---------------- layer 1 aggregate over x: 4 nodes/wave, 8-edge unroll + tail ------
__global__ __launch_bounds__(256) void k_l1_agg(const int* __restrict__ degv,
                                                const int* __restrict__ slots,
                                                const float* __restrict__ a_s,
                                                const float* __restrict__ a_d,
                                                const uint2* __restrict__ xbf,
                                                unsigned short* __restrict__ xagg) {
    int t = threadIdx.x;
    int wave = t >> 6, lane = t & 63;
    int q = lane >> 4, hl = lane & 15;
    int d = blockIdx.x * 16 + wave * 4 + q;          // 3125*16 = 50000 exact
    int beg = d << 6;
    int deg = degv[d];
    float4 ad = *(const float4*)(a_d + d * 4);
    float z0 = 0.f, z1 = 0.f, z2 = 0.f, z3 = 0.f;
    float a0[4] = {0.f, 0.f, 0.f, 0.f};
    float a1[4] = {0.f, 0.f, 0.f, 0.f};
    float a2[4] = {0.f, 0.f, 0.f, 0.f};
    float a3[4] = {0.f, 0.f, 0.f, 0.f};
    int i = 0;
    for (; i + 8 <= deg; i += 8) {
        int e0 = beg + i;
        int s[8]; uint2 u[8]; float4 as[8];
#pragma unroll
        for (int k = 0; k < 8; ++k) s[k] = slots[e0 + k];
#pragma unroll
        for (int k = 0; k < 8; ++k) u[k] = xbf[s[k] * 16 + hl];
#pragma unroll
        for (int k = 0; k < 8; ++k) as[k] = *(const float4*)(a_s + s[k] * 4);
#pragma unroll
        for (int k = 0; k < 8; ++k) {
            float e0h = __expf(leaky(as[k].x + ad.x));
            float e1h = __expf(leaky(as[k].y + ad.y));
            float e2h = __expf(leaky(as[k].z + ad.z));
            float e3h = __expf(leaky(as[k].w + ad.w));
            z0 += e0h; z1 += e1h; z2 += e2h; z3 += e3h;
            float c0 = lo16(u[k].x), c1 = hi16(u[k].x);
            float c2 = lo16(u[k].y), c3 = hi16(u[k].y);
            a0[0] += e0h * c0; a0[1] += e0h * c1; a0[2] += e0h * c2; a0[3] += e0h * c3;
            a1[0] += e1h * c0; a1[1] += e1h * c1; a1[2] += e1h * c2; a1[3] += e1h * c3;
            a2[0] += e2h * c0; a2[1] += e2h * c1; a2[2] += e2h * c2; a2[3] += e2h * c3;
            a3[0] += e3h * c0; a3[1] += e3h * c1; a3[2] += e3h * c2; a3[3] += e3h * c3;
        }
    }
    for (; i < deg; ++i) {
        int s = slots[beg + i];
        uint2 u = xbf[s * 16 + hl];
        float4 as = *(const float4*)(a_s + s * 4);
        float e0h = __expf(leaky(as.x + ad.x));
        float e1h = __expf(leaky(as.y + ad.y));
        float e2h = __expf(leaky(as.z + ad.z));
        float e3h = __expf(leaky(as.w + ad.w));
        z0 += e0h; z1 += e1h; z2 += e2h; z3 += e3h;
        float c0 = lo16(u.x), c1 = hi16(u.x);
        float c2 = lo16(u.y), c3 = hi16(u.y);
        a0[0] += e0h * c0; a0[1] += e0h * c1; a0[2] += e0h * c2; a0[3] += e0h * c3;
        a1[0] += e1h * c0; a1[1] += e1h * c1; a1[2] += e1h * c2; a1[3] += e1h * c3;
        a2[0] += e2h * c0; a2[1] += e2h * c1; a2[2] += e2h * c2; a2[3] += e2h * c3;
        a3[0] += e3h * c0; a3[1] += e3h * c1; a3[2] += e3h * c2; a3[3] += e3h * c3;
    }
    float i0 = 1.f / z0, i1 = 1.f / z1, i2 = 1.f / z2, i3 = 1.f / z3;
    uint2* xo = (uint2*)xagg;                        // 64 uint2 per row
    xo[d * 64 +  0 + hl] = make_uint2(pack2(a0[0] * i0, a0[1] * i0), pack2(a0[2] * i0, a0[3] * i0));
    xo[d * 64 + 16 + hl] = make_uint2(pack2(a1[0] * i1, a1[1] * i1), pack2(a1[2] * i1, a1[3] * i1));
    xo[d * 64 + 32 + hl] = make_uint2(pack2(a2[0] * i2, a2[1] * i2), pack2(a2[2] * i2, a2[3] * i2));
    xo[d * 64 + 48 + hl] = make_uint2(pack2(a3[0] * i3, a3[1] * i3), pack2(a3[2] * i3, a3[3] * i3));
}

// ---------------- fused layer-1+2 GEMM: xagg -> h1 (LDS) -> h2 + att logits ---------
__global__ __launch_bounds__(256) void k_gemm12(const unsigned short* __restrict__ xagg,
                                                const unsigned short* __restrict__ w1p,
                                                const float* __restrict__ b1,
                                                const unsigned short* __restrict__ w2p,
                                                const float* __restrict__ atts,
                                                const float* __restrict__ attd,
                                                unsigned short* __restrict__ h2bf,
                                                float* __restrict__ a_s,
                                                float* __restrict__ a_d) {
    __shared__ unsigned short hlds[4][16][264];   // padded row 528 B (16B-aligned)
    int t = threadIdx.x;
    int wave = t >> 6, lane = t & 63;
    int m0 = (blockIdx.x * 4 + wave) * 16;
    int l15 = lane & 15, quad = lane >> 4;
    bool active = m0 < N_NODES;

    if (active) {
        f32x4 acc1[H1][4];
#pragma unroll
        for (int h = 0; h < H1; ++h)
#pragma unroll
            for (int jj = 0; jj < 4; ++jj) acc1[h][jj] = (f32x4){0.f, 0.f, 0.f, 0.f};
        const unsigned short* arow = xagg + (m0 + l15) * C1;
#pragma unroll
        for (int h = 0; h < H1; ++h) {
#pragma unroll
            for (int k0 = 0; k0 < K1P; k0 += 32) {
                short8 av = *(const short8*)(arow + h * 64 + k0 + quad * 8);
#pragma unroll
                for (int jj = 0; jj < 4; ++jj) {
                    int c = h * 64 + jj * 16 + l15;
                    short8 bv = *(const short8*)(w1p + c * K1P + k0 + quad * 8);
                    acc1[h][jj] = __builtin_amdgcn_mfma_f32_16x16x32_bf16(av, bv, acc1[h][jj], 0, 0, 0);
                }
            }
        }
#pragma unroll
        for (int h = 0; h < H1; ++h)
#pragma unroll
            for (int jj = 0; jj < 4; ++jj) {
                int c = h * 64 + jj * 16 + l15;
                float bb = b1[c];
#pragma unroll
                for (int r = 0; r < 4; ++r)
                    hlds[wave][quad * 4 + r][c] = f2bfu(fmaxf(acc1[h][jj][r] + bb, 0.f));
            }
    }
    __syncthreads();
    if (!active) return;

    f32x4 acc2[8];
#pragma unroll
    for (int j = 0; j < 8; ++j) acc2[j] = (f32x4){0.f, 0.f, 0.f, 0.f};
    const unsigned short* a2row = &hlds[wave][l15][0] + quad * 8;
#pragma unroll
    for (int k0 = 0; k0 < C1; k0 += 32) {
        short8 av = *(const short8*)(a2row + k0);
#pragma unroll
        for (int j = 0; j < 8; ++j) {
            short8 bv = *(const short8*)(w2p + (j * 16 + l15) * C1 + k0 + quad * 8);
            acc2[j] = __builtin_amdgcn_mfma_f32_16x16x32_bf16(av, bv, acc2[j], 0, 0, 0);
        }
    }
    float ps[4] = {0.f, 0.f, 0.f, 0.f}, pd[4] = {0.f, 0.f, 0.f, 0.f};
#pragma unroll
    for (int j = 0; j < 8; ++j) {
        float as_ = atts[j * 16 + l15], ad_ = attd[j * 16 + l15];
#pragma unroll
        for (int r = 0; r < 4; ++r) {
            float v = acc2[j][r];
            h2bf[(m0 + quad * 4 + r) * C2 + j * 16 + l15] = f2bfu(v);
            ps[r] += v * as_;
            pd[r] += v * ad_;
        }
    }
#pragma unroll
    for (int r = 0; r < 4; ++r) {
#pragma unroll
        for (int o = 8; o > 0; o >>= 1) {
            ps[r] += __shfl_down(ps[r], o, 16);
            pd[r] += __shfl_down(pd[r], o, 16);
        }
        if (l15 == 0) {
            int n = m0 + quad * 4 + r;
            a_s[n] = ps[r];
            a_d[n] = pd[r];
        }
    }
}

// ---------------- layer 2 aggregate + pool: 2 nodes/wave, 8-edge unroll + tail ------
__global__ __launch_bounds__(256) void k_l2_aggpool(const int* __restrict__ degv,
                                                    const int* __restrict__ slots,
                                                    const float* __restrict__ a_s,
                                                    const float* __restrict__ a_d,
                                                    const unsigned short* __restrict__ h2bf,
                                                    const float* __restrict__ b2,
                                                    const int* __restrict__ batch,
                                                    float* __restrict__ pooled) {
    int t = threadIdx.x;
    int wave = t >> 6, lane = t & 63;
    int half = lane >> 5, hl = lane & 31;
    int d = blockIdx.x * 8 + wave * 2 + half;
    int beg = d << 6;
    int deg = degv[d];
    float ad = a_d[d];
    const uint2* rows = (const uint2*)h2bf;
    float a0 = 0.f, a1 = 0.f, a2 = 0.f, a3 = 0.f, z = 0.f;
    int i = 0;
    for (; i + 8 <= deg; i += 8) {
        int e0 = beg + i;
        int s[8]; uint2 u[8]; float ex[8];
#pragma unroll
        for (int k = 0; k < 8; ++k) s[k] = slots[e0 + k];
#pragma unroll
        for (int k = 0; k < 8; ++k) u[k] = rows[s[k] * 32 + hl];
#pragma unroll
        for (int k = 0; k < 8; ++k) ex[k] = __expf(leaky(a_s[s[k]] + ad));
#pragma unroll
        for (int k = 0; k < 8; ++k) {
            z  += ex[k];
            a0 += ex[k] * lo16(u[k].x); a1 += ex[k] * hi16(u[k].x);
            a2 += ex[k] * lo16(u[k].y); a3 += ex[k] * hi16(u[k].y);
        }
    }
    for (; i < deg; ++i) {
        int s = slots[beg + i];
        uint2 u = rows[s * 32 + hl];
        float ex = __expf(leaky(a_s[s] + ad));
        z  += ex;
        a0 += ex * lo16(u.x); a1 += ex * hi16(u.x);
        a2 += ex * lo16(u.y); a3 += ex * hi16(u.y);
    }
    float inv = 1.f / z;
    int c = hl * 4;
    float4 bv = *(const float4*)(b2 + c);
    float v0 = fmaxf(a0 * inv + bv.x, 0.f);
    float v1 = fmaxf(a1 * inv + bv.y, 0.f);
    float v2 = fmaxf(a2 * inv + bv.z, 0.f);
    float v3 = fmaxf(a3 * inv + bv.w, 0.f);
    int g = batch[d];
    int   gp = __shfl_xor(g,  32, 64);
    float w0 = __shfl_xor(v0, 32, 64);
    float w1 = __shfl_xor(v1, 32, 64);
    float w2 = __shfl_xor(v2, 32, 64);
    float w3 = __shfl_xor(v3, 32, 64);
    if (g == gp) {
        if (half == 0) {
            atomicAdd(&pooled[g * C2 + c],     v0 + w0);
            atomicAdd(&pooled[g * C2 + c + 1], v1 + w1);
            atomicAdd(&pooled[g * C2 + c + 2], v2 + w2);
            atomicAdd(&pooled[g * C2 + c + 3], v3 + w3);
        }
    } else {
        atomicAdd(&pooled[g * C2 + c],     v0);
        atomicAdd(&pooled[g * C2 + c + 1], v1);
        atomicAdd(&pooled[g * C2 + c + 2], v2);
        atomicAdd(&pooled[g * C2 + c + 3], v3);
    }
}

// ---------------- BN ----------------

__global__ __launch_bounds__(512) void k_bn(const float* __restrict__ pooled,
                                            const float* __restrict__ cnt,
                                            const float* __restrict__ gamma,
                                            const float* __restrict__ beta,
                                            float* __restrict__ out) {
    int c = blockIdx.x;
    int g = threadIdx.x;
    __shared__ float red[512];
    __shared__ float s_mu, s_var;
    float v = pooled[g * C2 + c] / fmaxf(cnt[g], 1.0f);
    red[g] = v;
    __syncthreads();
    for (int s = 256; s > 0; s >>= 1) {
        if (g < s) red[g] += red[g + s];
        __syncthreads();
    }
    if (g == 0) s_mu = red[0] * (1.0f / N_GRAPHS);
    __syncthreads();
    float dv = v - s_mu;
    red[g] = dv * dv;
    __syncthreads();
    for (int s = 256; s > 0; s >>= 1) {
        if (g < s) red[g] += red[g + s];
        __syncthreads();
    }
    if (g == 0) s_var = red[0] * (1.0f / N_GRAPHS);
    __syncthreads();
    out[g * C2 + c] = dv * rsqrtf(s_var + 1e-5f) * gamma[c] + beta[c];
}

extern "C" void kernel_launch(void* const* d_in, const int* in_sizes, int n_in,
                              void* d_out, int out_size, void* d_ws, size_t ws_size,
                              hipStream_t stream) {
    const float* x     = (const float*)d_in[0];
    const int*   eidx  = (const int*)d_in[1];
    const int*   batch = (const int*)d_in[2];
    const float* W1    = (const float*)d_in[3];
    const float* atts1 = (const float*)d_in[4];
    const float* attd1 = (const float*)d_in[5];
    const float* b1    = (const float*)d_in[6];
    const float* W2    = (const float*)d_in[7];
    const float* atts2 = (const float*)d_in[8];
    const float* attd2 = (const float*)d_in[9];
    const float* b2    = (const float*)d_in[10];
    const float* gamma = (const float*)d_in[11];
    const float* beta  = (const float*)d_in[12];
    float* out = (float*)d_out;
    float* ws  = (float*)d_ws;

    const int* src = eidx;
    const int* dst = eidx + N_EDGES;

    // workspace layout, float-element offsets (bf16 arrays use 2 shorts per float)
    const size_t o_xbf    = 0;           // 1,600,000
    const size_t o_xagg   = 1600000;     // 6,400,000
    const size_t o_h2bf   = 8000000;     // 3,200,000
    const size_t o_w1p    = 11200000;    // 8,192
    const size_t o_w2p    = 11208192;    // 16,384
    const size_t o_wproj  = 11224576;    // 512
    const size_t o_as1    = 11225088;    // 200,000
    const size_t o_ad1    = 11425088;    // 200,000
    const size_t o_as2    = 11625088;    // 50,000
    const size_t o_ad2    = 11675088;    // 50,000
    const size_t o_slots  = 11725088;    // 3,200,000 (50000 * 64 ints)
    // ---- contiguous zero block from here ----
    const size_t o_deg    = 14925088;    // 50,000
    const size_t o_pool   = 14975088;    // 65,536
    const size_t o_cnt    = 15040624;    // 512
    const size_t total    = 15041136;    // ~60 MB

    int* p_slots = (int*)(ws + o_slots);
    int* p_deg   = (int*)(ws + o_deg);
    unsigned short* p_xbf  = (unsigned short*)(ws + o_xbf);
    unsigned short* p_xagg = (unsigned short*)(ws + o_xagg);
    unsigned short* p_h2bf = (unsigned short*)(ws + o_h2bf);
    unsigned short* p_w1p  = (unsigned short*)(ws + o_w1p);
    unsigned short* p_w2p  = (unsigned short*)(ws + o_w2p);

    hipMemsetAsync(ws + o_deg, 0, (total - o_deg) * sizeof(float), stream);

    // ---- frontA: weights + projections + single-pass bucket build ----
    k_frontA<<<385 + NHIST, 256, 0, stream>>>(W1, W2, atts1, attd1, src, dst,
                                              p_w1p, p_w2p, ws + o_wproj,
                                              p_deg, p_slots);
    // ---- frontB: layer-1 logits + x cast + graph counts ----
    k_frontB<<<NATT, 256, 0, stream>>>(x, ws + o_wproj, batch, p_xbf,
                                       ws + o_as1, ws + o_ad1, ws + o_cnt);

    const int nagg1 = N_NODES / 16;             // 3125: 4 waves x 4 nodes per block
    const int nagg2 = N_NODES / 8;              // 6250: 4 waves x 2 nodes per block
    const int nmfma = (N_NODES + 63) / 64;      // 782: 4 waves x 16 nodes per block

    // ---- layer 1 aggregate + fused GEMM chain ----
    k_l1_agg<<<nagg1, 256, 0, stream>>>(p_deg, p_slots, ws + o_as1, ws + o_ad1,
                                        (const uint2*)p_xbf, p_xagg);
    k_gemm12<<<nmfma, 256, 0, stream>>>(p_xagg, p_w1p, b1, p_w2p, atts2, attd2,
                                        p_h2bf, ws + o_as2, ws + o_ad2);

    // ---- layer 2 aggregate + pool ----
    k_l2_aggpool<<<nagg2, 256, 0, stream>>>(p_deg, p_slots, ws + o_as2, ws + o_ad2,
                                            p_h2bf, b2, batch, ws + o_pool);

    // ---- BN ----
    k_bn<<<C2, 512, 0, stream>>>(ws + o_pool, ws + o_cnt, gamma, beta, out);
}

// Round 19
// 340.679 us; speedup vs baseline: 1.1265x; 1.1265x over previous
//
#include <hip/hip_runtime.h>
#include <hip/hip_bf16.h>
#include <math.h>

#define N_NODES  50000
#define N_EDGES  800000
#define E_TOT    850000   // + self loops
#define N_GRAPHS 512
#define IN_CH    58
#define K1P      64       // padded K for layer-1 MFMA
#define C1       256      // HEADS1 * H = 4*64
#define H1       4
#define C2       128
#define NEG_SLOPE 0.2f
#define SLOT_CAP 64       // fixed bucket capacity; P(Poisson(17) > 63) < 1e-13
#define NHIST    3321     // ceil(850000/256)
#define NATT     12500    // ceil(50000/4)

typedef __attribute__((ext_vector_type(8))) short short8;
typedef __attribute__((ext_vector_type(4))) float f32x4;

__device__ __forceinline__ float lo16(unsigned u) { return __uint_as_float(u << 16); }
__device__ __forceinline__ float hi16(unsigned u) { return __uint_as_float(u & 0xffff0000u); }
__device__ __forceinline__ float leaky(float e) { return e > 0.f ? e : NEG_SLOPE * e; }
__device__ __forceinline__ unsigned short f2bfu(float v) {
    __hip_bfloat16 b = __float2bfloat16(v);
    return *(unsigned short*)&b;
}
__device__ __forceinline__ unsigned pack2(float lo, float hi) {
    return (unsigned)f2bfu(lo) | ((unsigned)f2bfu(hi) << 16);
}

// ---- frontA: weight prep + att projections (tiny) ----
__global__ __launch_bounds__(256) void k_frontA(const float* __restrict__ W1,
                                                const float* __restrict__ W2,
                                                const float* __restrict__ atts1,
                                                const float* __restrict__ attd1,
                                                unsigned short* __restrict__ w1p,
                                                unsigned short* __restrict__ w2p,
                                                float* __restrict__ wproj) {
    int b = blockIdx.x;
    int t = threadIdx.x;
    if (b < 256) {                     // w1p[c][k] = bf16(W1[k][c]), zero-pad k>=58
        if (t < K1P) {
            float v = (t < IN_CH) ? W1[t * C1 + b] : 0.f;
            w1p[b * K1P + t] = f2bfu(v);
        }
    } else if (b < 384) {              // w2p[n][k] = bf16(W2[k][n])
        int n = b - 256;
        w2p[n * C1 + t] = f2bfu(W2[t * C2 + n]);
    } else {                           // att projections through W1
        int k = t >> 2, h = t & 3;
        float s = 0.f, dd = 0.f;
        if (k < IN_CH) {
            for (int j = 0; j < 64; ++j) {
                float wv = W1[k * C1 + h * 64 + j];
                s  += wv * atts1[h * 64 + j];
                dd += wv * attd1[h * 64 + j];
            }
        }
        wproj[t] = s;
        wproj[256 + t] = dd;
    }
}

// ---- mid: single-pass bucket build (hist+scatter) + layer-1 logits/x-cast ----
__global__ __launch_bounds__(256) void k_mid(const int* __restrict__ src,
                                             const int* __restrict__ dst,
                                             int* __restrict__ deg,
                                             int* __restrict__ slots,
                                             const float* __restrict__ x,
                                             const float* __restrict__ wproj,
                                             unsigned short* __restrict__ xbf,
                                             float* __restrict__ a_s,
                                             float* __restrict__ a_d) {
    int b = blockIdx.x;
    int t = threadIdx.x;
    if (b < NHIST) {                   // fused histogram + scatter into fixed buckets
        int j = b * 256 + t;
        if (j < E_TOT) {
            int s, d;
            if (j < N_EDGES) { s = src[j]; d = dst[j]; } else { s = d = j - N_EDGES; }
            int pos = atomicAdd(&deg[d], 1);
            slots[(d << 6) + pos] = s;
        }
    } else {                           // layer-1 logits + x -> bf16 cast
        int n = (b - NHIST) * 4 + (t >> 6);
        int lane = t & 63;
        float xv = (lane < IN_CH) ? x[n * IN_CH + lane] : 0.f;
        xbf[n * K1P + lane] = f2bfu(xv);
        float ps0 = xv * wproj[lane * 4 + 0], ps1 = xv * wproj[lane * 4 + 1];
        float ps2 = xv * wproj[lane * 4 + 2], ps3 = xv * wproj[lane * 4 + 3];
        float pd0 = xv * wproj[256 + lane * 4 + 0], pd1 = xv * wproj[256 + lane * 4 + 1];
        float pd2 = xv * wproj[256 + lane * 4 + 2], pd3 = xv * wproj[256 + lane * 4 + 3];
#pragma unroll
        for (int o = 32; o > 0; o >>= 1) {
            ps0 += __shfl_down(ps0, o, 64); ps1 += __shfl_down(ps1, o, 64);
            ps2 += __shfl_down(ps2, o, 64); ps3 += __shfl_down(ps3, o, 64);
            pd0 += __shfl_down(pd0, o, 64); pd1 += __shfl_down(pd1, o, 64);
            pd2 += __shfl_down(pd2, o, 64); pd3 += __shfl_down(pd3, o, 64);
        }
        if (lane == 0) {
            *(float4*)(a_s + n * 4) = make_float4(ps0, ps1, ps2, ps3);
            *(float4*)(a_d + n * 4) = make_float4(pd0, pd1, pd2, pd3);
        }
    }
}

// ---------------- layer 1 aggregate over x: 4 nodes/wave, 8-edge unroll + tail ------
__global__ __launch_bounds__(256) void k_l1_agg(const int* __restrict__ degv,
                                                const int* __restrict__ slots,
                                                const float* __restrict__ a_s,
                                                const float* __restrict__ a_d,
                                                const uint2* __restrict__ xbf,
                                                unsigned short* __restrict__ xagg) {
    int t = threadIdx.x;
    int wave = t >> 6, lane = t & 63;
    int q = lane >> 4, hl = lane & 15;
    int d = blockIdx.x * 16 + wave * 4 + q;          // 3125*16 = 50000 exact
    int beg = d << 6;
    int deg = degv[d];
    float4 ad = *(const float4*)(a_d + d * 4);
    float z0 = 0.f, z1 = 0.f, z2 = 0.f, z3 = 0.f;
    float a0[4] = {0.f, 0.f, 0.f, 0.f};
    float a1[4] = {0.f, 0.f, 0.f, 0.f};
    float a2[4] = {0.f, 0.f, 0.f, 0.f};
    float a3[4] = {0.f, 0.f, 0.f, 0.f};
    int i = 0;
    for (; i + 8 <= deg; i += 8) {
        int e0 = beg + i;
        int s[8]; uint2 u[8]; float4 as[8];
#pragma unroll
        for (int k = 0; k < 8; ++k) s[k] = slots[e0 + k];
#pragma unroll
        for (int k = 0; k < 8; ++k) u[k] = xbf[s[k] * 16 + hl];
#pragma unroll
        for (int k = 0; k < 8; ++k) as[k] = *(const float4*)(a_s + s[k] * 4);
#pragma unroll
        for (int k = 0; k < 8; ++k) {
            float e0h = __expf(leaky(as[k].x + ad.x));
            float e1h = __expf(leaky(as[k].y + ad.y));
            float e2h = __expf(leaky(as[k].z + ad.z));
            float e3h = __expf(leaky(as[k].w + ad.w));
            z0 += e0h; z1 += e1h; z2 += e2h; z3 += e3h;
            float c0 = lo16(u[k].x), c1 = hi16(u[k].x);
            float c2 = lo16(u[k].y), c3 = hi16(u[k].y);
            a0[0] += e0h * c0; a0[1] += e0h * c1; a0[2] += e0h * c2; a0[3] += e0h * c3;
            a1[0] += e1h * c0; a1[1] += e1h * c1; a1[2] += e1h * c2; a1[3] += e1h * c3;
            a2[0] += e2h * c0; a2[1] += e2h * c1; a2[2] += e2h * c2; a2[3] += e2h * c3;
            a3[0] += e3h * c0; a3[1] += e3h * c1; a3[2] += e3h * c2; a3[3] += e3h * c3;
        }
    }
    for (; i < deg; ++i) {
        int s = slots[beg + i];
        uint2 u = xbf[s * 16 + hl];
        float4 as = *(const float4*)(a_s + s * 4);
        float e0h = __expf(leaky(as.x + ad.x));
        float e1h = __expf(leaky(as.y + ad.y));
        float e2h = __expf(leaky(as.z + ad.z));
        float e3h = __expf(leaky(as.w + ad.w));
        z0 += e0h; z1 += e1h; z2 += e2h; z3 += e3h;
        float c0 = lo16(u.x), c1 = hi16(u.x);
        float c2 = lo16(u.y), c3 = hi16(u.y);
        a0[0] += e0h * c0; a0[1] += e0h * c1; a0[2] += e0h * c2; a0[3] += e0h * c3;
        a1[0] += e1h * c0; a1[1] += e1h * c1; a1[2] += e1h * c2; a1[3] += e1h * c3;
        a2[0] += e2h * c0; a2[1] += e2h * c1; a2[2] += e2h * c2; a2[3] += e2h * c3;
        a3[0] += e3h * c0; a3[1] += e3h * c1; a3[2] += e3h * c2; a3[3] += e3h * c3;
    }
    float i0 = 1.f / z0, i1 = 1.f / z1, i2 = 1.f / z2, i3 = 1.f / z3;
    uint2* xo = (uint2*)xagg;                        // 64 uint2 per row
    xo[d * 64 +  0 + hl] = make_uint2(pack2(a0[0] * i0, a0[1] * i0), pack2(a0[2] * i0, a0[3] * i0));
    xo[d * 64 + 16 + hl] = make_uint2(pack2(a1[0] * i1, a1[1] * i1), pack2(a1[2] * i1, a1[3] * i1));
    xo[d * 64 + 32 + hl] = make_uint2(pack2(a2[0] * i2, a2[1] * i2), pack2(a2[2] * i2, a2[3] * i2));
    xo[d * 64 + 48 + hl] = make_uint2(pack2(a3[0] * i3, a3[1] * i3), pack2(a3[2] * i3, a3[3] * i3));
}

// ---------------- fused layer-1+2 GEMM: xagg -> h1 (LDS) -> h2 + att logits ---------
__global__ __launch_bounds__(256) void k_gemm12(const unsigned short* __restrict__ xagg,
                                                const unsigned short* __restrict__ w1p,
                                                const float* __restrict__ b1,
                                                const unsigned short* __restrict__ w2p,
                                                const float* __restrict__ atts,
                                                const float* __restrict__ attd,
                                                unsigned short* __restrict__ h2bf,
                                                float* __restrict__ a_s,
                                                float* __restrict__ a_d) {
    __shared__ unsigned short hlds[4][16][264];   // padded row 528 B (16B-aligned)
    int t = threadIdx.x;
    int wave = t >> 6, lane = t & 63;
    int m0 = (blockIdx.x * 4 + wave) * 16;
    int l15 = lane & 15, quad = lane >> 4;
    bool active = m0 < N_NODES;

    if (active) {
        f32x4 acc1[H1][4];
#pragma unroll
        for (int h = 0; h < H1; ++h)
#pragma unroll
            for (int jj = 0; jj < 4; ++jj) acc1[h][jj] = (f32x4){0.f, 0.f, 0.f, 0.f};
        const unsigned short* arow = xagg + (m0 + l15) * C1;
#pragma unroll
        for (int h = 0; h < H1; ++h) {
#pragma unroll
            for (int k0 = 0; k0 < K1P; k0 += 32) {
                short8 av = *(const short8*)(arow + h * 64 + k0 + quad * 8);
#pragma unroll
                for (int jj = 0; jj < 4; ++jj) {
                    int c = h * 64 + jj * 16 + l15;
                    short8 bv = *(const short8*)(w1p + c * K1P + k0 + quad * 8);
                    acc1[h][jj] = __builtin_amdgcn_mfma_f32_16x16x32_bf16(av, bv, acc1[h][jj], 0, 0, 0);
                }
            }
        }
#pragma unroll
        for (int h = 0; h < H1; ++h)
#pragma unroll
            for (int jj = 0; jj < 4; ++jj) {
                int c = h * 64 + jj * 16 + l15;
                float bb = b1[c];
#pragma unroll
                for (int r = 0; r < 4; ++r)
                    hlds[wave][quad * 4 + r][c] = f2bfu(fmaxf(acc1[h][jj][r] + bb, 0.f));
            }
    }
    __syncthreads();
    if (!active) return;

    f32x4 acc2[8];
#pragma unroll
    for (int j = 0; j < 8; ++j) acc2[j] = (f32x4){0.f, 0.f, 0.f, 0.f};
    const unsigned short* a2row = &hlds[wave][l15][0] + quad * 8;
#pragma unroll
    for (int k0 = 0; k0 < C1; k0 += 32) {
        short8 av = *(const short8*)(a2row + k0);
#pragma unroll
        for (int j = 0; j < 8; ++j) {
            short8 bv = *(const short8*)(w2p + (j * 16 + l15) * C1 + k0 + quad * 8);
            acc2[j] = __builtin_amdgcn_mfma_f32_16x16x32_bf16(av, bv, acc2[j], 0, 0, 0);
        }
    }
    float ps[4] = {0.f, 0.f, 0.f, 0.f}, pd[4] = {0.f, 0.f, 0.f, 0.f};
#pragma unroll
    for (int j = 0; j < 8; ++j) {
        float as_ = atts[j * 16 + l15], ad_ = attd[j * 16 + l15];
#pragma unroll
        for (int r = 0; r < 4; ++r) {
            float v = acc2[j][r];
            h2bf[(m0 + quad * 4 + r) * C2 + j * 16 + l15] = f2bfu(v);
            ps[r] += v * as_;
            pd[r] += v * ad_;
        }
    }
#pragma unroll
    for (int r = 0; r < 4; ++r) {
#pragma unroll
        for (int o = 8; o > 0; o >>= 1) {
            ps[r] += __shfl_down(ps[r], o, 16);
            pd[r] += __shfl_down(pd[r], o, 16);
        }
        if (l15 == 0) {
            int n = m0 + quad * 4 + r;
            a_s[n] = ps[r];
            a_d[n] = pd[r];
        }
    }
}

// ---------------- layer 2 aggregate + pool: 2 nodes/wave, 8-edge unroll + tail ------
__global__ __launch_bounds__(256) void k_l2_aggpool(const int* __restrict__ degv,
                                                    const int* __restrict__ slots,
                                                    const float* __restrict__ a_s,
                                                    const float* __restrict__ a_d,
                                                    const unsigned short* __restrict__ h2bf,
                                                    const float* __restrict__ b2,
                                                    const int* __restrict__ batch,
                                                    float* __restrict__ pooled) {
    int t = threadIdx.x;
    int wave = t >> 6, lane = t & 63;
    int half = lane >> 5, hl = lane & 31;
    int d = blockIdx.x * 8 + wave * 2 + half;
    int beg = d << 6;
    int deg = degv[d];
    float ad = a_d[d];
    const uint2* rows = (const uint2*)h2bf;
    float a0 = 0.f, a1 = 0.f, a2 = 0.f, a3 = 0.f, z = 0.f;
    int i = 0;
    for (; i + 8 <= deg; i += 8) {
        int e0 = beg + i;
        int s[8]; uint2 u[8]; float ex[8];
#pragma unroll
        for (int k = 0; k < 8; ++k) s[k] = slots[e0 + k];
#pragma unroll
        for (int k = 0; k < 8; ++k) u[k] = rows[s[k] * 32 + hl];
#pragma unroll
        for (int k = 0; k < 8; ++k) ex[k] = __expf(leaky(a_s[s[k]] + ad));
#pragma unroll
        for (int k = 0; k < 8; ++k) {
            z  += ex[k];
            a0 += ex[k] * lo16(u[k].x); a1 += ex[k] * hi16(u[k].x);
            a2 += ex[k] * lo16(u[k].y); a3 += ex[k] * hi16(u[k].y);
        }
    }
    for (; i < deg; ++i) {
        int s = slots[beg + i];
        uint2 u = rows[s * 32 + hl];
        float ex = __expf(leaky(a_s[s] + ad));
        z  += ex;
        a0 += ex * lo16(u.x); a1 += ex * hi16(u.x);
        a2 += ex * lo16(u.y); a3 += ex * hi16(u.y);
    }
    float inv = 1.f / z;
    int c = hl * 4;
    float4 bv = *(const float4*)(b2 + c);
    float v0 = fmaxf(a0 * inv + bv.x, 0.f);
    float v1 = fmaxf(a1 * inv + bv.y, 0.f);
    float v2 = fmaxf(a2 * inv + bv.z, 0.f);
    float v3 = fmaxf(a3 * inv + bv.w, 0.f);
    int g = batch[d];
    int   gp = __shfl_xor(g,  32, 64);
    float w0 = __shfl_xor(v0, 32, 64);
    float w1 = __shfl_xor(v1, 32, 64);
    float w2 = __shfl_xor(v2, 32, 64);
    float w3 = __shfl_xor(v3, 32, 64);
    if (g == gp) {
        if (half == 0) {
            atomicAdd(&pooled[g * C2 + c],     v0 + w0);
            atomicAdd(&pooled[g * C2 + c + 1], v1 + w1);
            atomicAdd(&pooled[g * C2 + c + 2], v2 + w2);
            atomicAdd(&pooled[g * C2 + c + 3], v3 + w3);
        }
    } else {
        atomicAdd(&pooled[g * C2 + c],     v0);
        atomicAdd(&pooled[g * C2 + c + 1], v1);
        atomicAdd(&pooled[g * C2 + c + 2], v2);
        atomicAdd(&pooled[g * C2 + c + 3], v3);
    }
}

// ---------------- BN: cnt via binary search on sorted batch (no atomics) ----------
__global__ __launch_bounds__(512) void k_bn(const float* __restrict__ pooled,
                                            const int* __restrict__ batch,
                                            const float* __restrict__ gamma,
                                            const float* __restrict__ beta,
                                            float* __restrict__ out) {
    int c = blockIdx.x;
    int g = threadIdx.x;
    // cnt[g] = (first index >= g+1) - (first index >= g)
    int lo = 0, hi = N_NODES;
    while (lo < hi) { int m = (lo + hi) >> 1; if (batch[m] < g) lo = m + 1; else hi = m; }
    int lo2 = lo, hi2 = N_NODES;
    while (lo2 < hi2) { int m = (lo2 + hi2) >> 1; if (batch[m] < g + 1) lo2 = m + 1; else hi2 = m; }
    float cntg = (float)(hi2 - lo);

    __shared__ float red[512];
    __shared__ float s_mu, s_var;
    float v = pooled[g * C2 + c] / fmaxf(cntg, 1.0f);
    red[g] = v;
    __syncthreads();
    for (int s = 256; s > 0; s >>= 1) {
        if (g < s) red[g] += red[g + s];
        __syncthreads();
    }
    if (g == 0) s_mu = red[0] * (1.0f / N_GRAPHS);
    __syncthreads();
    float dv = v - s_mu;
    red[g] = dv * dv;
    __syncthreads();
    for (int s = 256; s > 0; s >>= 1) {
        if (g < s) red[g] += red[g + s];
        __syncthreads();
    }
    if (g == 0) s_var = red[0] * (1.0f / N_GRAPHS);
    __syncthreads();
    out[g * C2 + c] = dv * rsqrtf(s_var + 1e-5f) * gamma[c] + beta[c];
}

extern "C" void kernel_launch(void* const* d_in, const int* in_sizes, int n_in,
                              void* d_out, int out_size, void* d_ws, size_t ws_size,
                              hipStream_t stream) {
    const float* x     = (const float*)d_in[0];
    const int*   eidx  = (const int*)d_in[1];
    const int*   batch = (const int*)d_in[2];
    const float* W1    = (const float*)d_in[3];
    const float* atts1 = (const float*)d_in[4];
    const float* attd1 = (const float*)d_in[5];
    const float* b1    = (const float*)d_in[6];
    const float* W2    = (const float*)d_in[7];
    const float* atts2 = (const float*)d_in[8];
    const float* attd2 = (const float*)d_in[9];
    const float* b2    = (const float*)d_in[10];
    const float* gamma = (const float*)d_in[11];
    const float* beta  = (const float*)d_in[12];
    float* out = (float*)d_out;
    float* ws  = (float*)d_ws;

    const int* src = eidx;
    const int* dst = eidx + N_EDGES;

    // workspace layout, float-element offsets (bf16 arrays use 2 shorts per float)
    const size_t o_xbf    = 0;           // 1,600,000
    const size_t o_xagg   = 1600000;     // 6,400,000
    const size_t o_h2bf   = 8000000;     // 3,200,000
    const size_t o_w1p    = 11200000;    // 8,192
    const size_t o_w2p    = 11208192;    // 16,384
    const size_t o_wproj  = 11224576;    // 512
    const size_t o_as1    = 11225088;    // 200,000
    const size_t o_ad1    = 11425088;    // 200,000
    const size_t o_as2    = 11625088;    // 50,000
    const size_t o_ad2    = 11675088;    // 50,000
    const size_t o_slots  = 11725088;    // 3,200,000 (50000 * 64 ints)
    // ---- contiguous zero block from here ----
    const size_t o_deg    = 14925088;    // 50,000
    const size_t o_pool   = 14975088;    // 65,536
    const size_t total    = 15040624;    // ~60 MB

    int* p_slots = (int*)(ws + o_slots);
    int* p_deg   = (int*)(ws + o_deg);
    unsigned short* p_xbf  = (unsigned short*)(ws + o_xbf);
    unsigned short* p_xagg = (unsigned short*)(ws + o_xagg);
    unsigned short* p_h2bf = (unsigned short*)(ws + o_h2bf);
    unsigned short* p_w1p  = (unsigned short*)(ws + o_w1p);
    unsigned short* p_w2p  = (unsigned short*)(ws + o_w2p);

    hipMemsetAsync(ws + o_deg, 0, (total - o_deg) * sizeof(float), stream);

    // ---- frontA: weights + att projections ----
    k_frontA<<<385, 256, 0, stream>>>(W1, W2, atts1, attd1,
                                      p_w1p, p_w2p, ws + o_wproj);
    // ---- mid: single-pass bucket build + layer-1 logits / x cast (overlapped) ----
    k_mid<<<NHIST + NATT, 256, 0, stream>>>(src, dst, p_deg, p_slots,
                                            x, ws + o_wproj, p_xbf,
                                            ws + o_as1, ws + o_ad1);

    const int nagg1 = N_NODES / 16;             // 3125: 4 waves x 4 nodes per block
    const int nagg2 = N_NODES / 8;              // 6250: 4 waves x 2 nodes per block
    const int nmfma = (N_NODES + 63) / 64;      // 782: 4 waves x 16 nodes per block

    // ---- layer 1 aggregate + fused GEMM chain ----
    k_l1_agg<<<nagg1, 256, 0, stream>>>(p_deg, p_slots, ws + o_as1, ws + o_ad1,
                                        (const uint2*)p_xbf, p_xagg);
    k_gemm12<<<nmfma, 256, 0, stream>>>(p_xagg, p_w1p, b1, p_w2p, atts2, attd2,
                                        p_h2bf, ws + o_as2, ws + o_ad2);

    // ---- layer 2 aggregate + pool ----
    k_l2_aggpool<<<nagg2, 256, 0, stream>>>(p_deg, p_slots, ws + o_as2, ws + o_ad2,
                                            p_h2bf, b2, batch, ws + o_pool);

    // ---- BN (cnt via binary search, no atomics) ----
    k_bn<<<C2, 512, 0, stream>>>(ws + o_pool, batch, gamma, beta, out);
}

// Round 20
// 329.389 us; speedup vs baseline: 1.1651x; 1.0343x over previous
//
#include <hip/hip_runtime.h>
#include <hip/hip_bf16.h>
#include <math.h>

#define N_NODES  50000
#define N_EDGES  800000
#define E_TOT    850000   // + self loops
#define N_GRAPHS 512
#define IN_CH    58
#define K1P      64       // padded K for layer-1 MFMA
#define C1       256      // HEADS1 * H = 4*64
#define H1       4
#define C2       128
#define NEG_SLOPE 0.2f
#define SLOT_CAP 64       // fixed bucket capacity; P(Poisson(17) > 63) < 1e-13
#define NBUILD   831      // ceil(850000 / (256*4)) -- 4 edges per thread
#define NATT     12500    // ceil(50000/4)

typedef __attribute__((ext_vector_type(8))) short short8;
typedef __attribute__((ext_vector_type(4))) float f32x4;

__device__ __forceinline__ float lo16(unsigned u) { return __uint_as_float(u << 16); }
__device__ __forceinline__ float hi16(unsigned u) { return __uint_as_float(u & 0xffff0000u); }
__device__ __forceinline__ float leaky(float e) { return e > 0.f ? e : NEG_SLOPE * e; }
__device__ __forceinline__ unsigned short f2bfu(float v) {
    __hip_bfloat16 b = __float2bfloat16(v);
    return *(unsigned short*)&b;
}
__device__ __forceinline__ unsigned pack2(float lo, float hi) {
    return (unsigned)f2bfu(lo) | ((unsigned)f2bfu(hi) << 16);
}

// ---- frontA: weight prep + att projections (tiny) ----
__global__ __launch_bounds__(256) void k_frontA(const float* __restrict__ W1,
                                                const float* __restrict__ W2,
                                                const float* __restrict__ atts1,
                                                const float* __restrict__ attd1,
                                                unsigned short* __restrict__ w1p,
                                                unsigned short* __restrict__ w2p,
                                                float* __restrict__ wproj) {
    int b = blockIdx.x;
    int t = threadIdx.x;
    if (b < 256) {                     // w1p[c][k] = bf16(W1[k][c]), zero-pad k>=58
        if (t < K1P) {
            float v = (t < IN_CH) ? W1[t * C1 + b] : 0.f;
            w1p[b * K1P + t] = f2bfu(v);
        }
    } else if (b < 384) {              // w2p[n][k] = bf16(W2[k][n])
        int n = b - 256;
        w2p[n * C1 + t] = f2bfu(W2[t * C2 + n]);
    } else {                           // att projections through W1
        int k = t >> 2, h = t & 3;
        float s = 0.f, dd = 0.f;
        if (k < IN_CH) {
            for (int j = 0; j < 64; ++j) {
                float wv = W1[k * C1 + h * 64 + j];
                s  += wv * atts1[h * 64 + j];
                dd += wv * attd1[h * 64 + j];
            }
        }
        wproj[t] = s;
        wproj[256 + t] = dd;
    }
}

// ---- mid: bucket build (4 edges/thread, interleaved chains) + layer-1 logits ----
__global__ __launch_bounds__(256) void k_mid(const int* __restrict__ src,
                                             const int* __restrict__ dst,
                                             int* __restrict__ deg,
                                             int* __restrict__ slots,
                                             const float* __restrict__ x,
                                             const float* __restrict__ wproj,
                                             unsigned short* __restrict__ xbf,
                                             float* __restrict__ a_s,
                                             float* __restrict__ a_d) {
    int b = blockIdx.x;
    int t = threadIdx.x;
    if (b < NBUILD) {                  // histogram + scatter, 4 independent chains
        int j0 = (b * 256 + t) * 4;
        int s[4], d[4], pos[4];
        bool v[4];
#pragma unroll
        for (int k = 0; k < 4; ++k) {
            int j = j0 + k;
            v[k] = j < E_TOT;
            if (v[k]) {
                if (j < N_EDGES) { s[k] = src[j]; d[k] = dst[j]; }
                else             { s[k] = d[k] = j - N_EDGES; }
            }
        }
#pragma unroll
        for (int k = 0; k < 4; ++k)
            if (v[k]) pos[k] = atomicAdd(&deg[d[k]], 1);
#pragma unroll
        for (int k = 0; k < 4; ++k)
            if (v[k]) slots[(d[k] << 6) + pos[k]] = s[k];
    } else {                           // layer-1 logits + x -> bf16 cast
        int n = (b - NBUILD) * 4 + (t >> 6);
        int lane = t & 63;
        float xv = (lane < IN_CH) ? x[n * IN_CH + lane] : 0.f;
        xbf[n * K1P + lane] = f2bfu(xv);
        float ps0 = xv * wproj[lane * 4 + 0], ps1 = xv * wproj[lane * 4 + 1];
        float ps2 = xv * wproj[lane * 4 + 2], ps3 = xv * wproj[lane * 4 + 3];
        float pd0 = xv * wproj[256 + lane * 4 + 0], pd1 = xv * wproj[256 + lane * 4 + 1];
        float pd2 = xv * wproj[256 + lane * 4 + 2], pd3 = xv * wproj[256 + lane * 4 + 3];
#pragma unroll
        for (int o = 32; o > 0; o >>= 1) {
            ps0 += __shfl_down(ps0, o, 64); ps1 += __shfl_down(ps1, o, 64);
            ps2 += __shfl_down(ps2, o, 64); ps3 += __shfl_down(ps3, o, 64);
            pd0 += __shfl_down(pd0, o, 64); pd1 += __shfl_down(pd1, o, 64);
            pd2 += __shfl_down(pd2, o, 64); pd3 += __shfl_down(pd3, o, 64);
        }
        if (lane == 0) {
            *(float4*)(a_s + n * 4) = make_float4(ps0, ps1, ps2, ps3);
            *(float4*)(a_d + n * 4) = make_float4(pd0, pd1, pd2, pd3);
        }
    }
}

// ---------------- layer 1 aggregate over x: 4 nodes/wave, 8-edge unroll + tail ------
__global__ __launch_bounds__(256) void k_l1_agg(const int* __restrict__ degv,
                                                const int* __restrict__ slots,
                                                const float* __restrict__ a_s,
                                                const float* __restrict__ a_d,
                                                const uint2* __restrict__ xbf,
                                                unsigned short* __restrict__ xagg) {
    int t = threadIdx.x;
    int wave = t >> 6, lane = t & 63;
    int q = lane >> 4, hl = lane & 15;
    int d = blockIdx.x * 16 + wave * 4 + q;          // 3125*16 = 50000 exact
    int beg = d << 6;
    int deg = degv[d];
    float4 ad = *(const float4*)(a_d + d * 4);
    float z0 = 0.f, z1 = 0.f, z2 = 0.f, z3 = 0.f;
    float a0[4] = {0.f, 0.f, 0.f, 0.f};
    float a1[4] = {0.f, 0.f, 0.f, 0.f};
    float a2[4] = {0.f, 0.f, 0.f, 0.f};
    float a3[4] = {0.f, 0.f, 0.f, 0.f};
    int i = 0;
    for (; i + 8 <= deg; i += 8) {
        int e0 = beg + i;
        int s[8]; uint2 u[8]; float4 as[8];
#pragma unroll
        for (int k = 0; k < 8; ++k) s[k] = slots[e0 + k];
#pragma unroll
        for (int k = 0; k < 8; ++k) u[k] = xbf[s[k] * 16 + hl];
#pragma unroll
        for (int k = 0; k < 8; ++k) as[k] = *(const float4*)(a_s + s[k] * 4);
#pragma unroll
        for (int k = 0; k < 8; ++k) {
            float e0h = __expf(leaky(as[k].x + ad.x));
            float e1h = __expf(leaky(as[k].y + ad.y));
            float e2h = __expf(leaky(as[k].z + ad.z));
            float e3h = __expf(leaky(as[k].w + ad.w));
            z0 += e0h; z1 += e1h; z2 += e2h; z3 += e3h;
            float c0 = lo16(u[k].x), c1 = hi16(u[k].x);
            float c2 = lo16(u[k].y), c3 = hi16(u[k].y);
            a0[0] += e0h * c0; a0[1] += e0h * c1; a0[2] += e0h * c2; a0[3] += e0h * c3;
            a1[0] += e1h * c0; a1[1] += e1h * c1; a1[2] += e1h * c2; a1[3] += e1h * c3;
            a2[0] += e2h * c0; a2[1] += e2h * c1; a2[2] += e2h * c2; a2[3] += e2h * c3;
            a3[0] += e3h * c0; a3[1] += e3h * c1; a3[2] += e3h * c2; a3[3] += e3h * c3;
        }
    }
    for (; i < deg; ++i) {
        int s = slots[beg + i];
        uint2 u = xbf[s * 16 + hl];
        float4 as = *(const float4*)(a_s + s * 4);
        float e0h = __expf(leaky(as.x + ad.x));
        float e1h = __expf(leaky(as.y + ad.y));
        float e2h = __expf(leaky(as.z + ad.z));
        float e3h = __expf(leaky(as.w + ad.w));
        z0 += e0h; z1 += e1h; z2 += e2h; z3 += e3h;
        float c0 = lo16(u.x), c1 = hi16(u.x);
        float c2 = lo16(u.y), c3 = hi16(u.y);
        a0[0] += e0h * c0; a0[1] += e0h * c1; a0[2] += e0h * c2; a0[3] += e0h * c3;
        a1[0] += e1h * c0; a1[1] += e1h * c1; a1[2] += e1h * c2; a1[3] += e1h * c3;
        a2[0] += e2h * c0; a2[1] += e2h * c1; a2[2] += e2h * c2; a2[3] += e2h * c3;
        a3[0] += e3h * c0; a3[1] += e3h * c1; a3[2] += e3h * c2; a3[3] += e3h * c3;
    }
    float i0 = 1.f / z0, i1 = 1.f / z1, i2 = 1.f / z2, i3 = 1.f / z3;
    uint2* xo = (uint2*)xagg;                        // 64 uint2 per row
    xo[d * 64 +  0 + hl] = make_uint2(pack2(a0[0] * i0, a0[1] * i0), pack2(a0[2] * i0, a0[3] * i0));
    xo[d * 64 + 16 + hl] = make_uint2(pack2(a1[0] * i1, a1[1] * i1), pack2(a1[2] * i1, a1[3] * i1));
    xo[d * 64 + 32 + hl] = make_uint2(pack2(a2[0] * i2, a2[1] * i2), pack2(a2[2] * i2, a2[3] * i2));
    xo[d * 64 + 48 + hl] = make_uint2(pack2(a3[0] * i3, a3[1] * i3), pack2(a3[2] * i3, a3[3] * i3));
}

// ---------------- fused layer-1+2 GEMM: xagg -> h1 (LDS) -> h2 + att logits ---------
__global__ __launch_bounds__(256) void k_gemm12(const unsigned short* __restrict__ xagg,
                                                const unsigned short* __restrict__ w1p,
                                                const float* __restrict__ b1,
                                                const unsigned short* __restrict__ w2p,
                                                const float* __restrict__ atts,
                                                const float* __restrict__ attd,
                                                unsigned short* __restrict__ h2bf,
                                                float* __restrict__ a_s,
                                                float* __restrict__ a_d) {
    __shared__ unsigned short hlds[4][16][264];   // padded row 528 B (16B-aligned)
    int t = threadIdx.x;
    int wave = t >> 6, lane = t & 63;
    int m0 = (blockIdx.x * 4 + wave) * 16;
    int l15 = lane & 15, quad = lane >> 4;
    bool active = m0 < N_NODES;

    if (active) {
        f32x4 acc1[H1][4];
#pragma unroll
        for (int h = 0; h < H1; ++h)
#pragma unroll
            for (int jj = 0; jj < 4; ++jj) acc1[h][jj] = (f32x4){0.f, 0.f, 0.f, 0.f};
        const unsigned short* arow = xagg + (m0 + l15) * C1;
#pragma unroll
        for (int h = 0; h < H1; ++h) {
#pragma unroll
            for (int k0 = 0; k0 < K1P; k0 += 32) {
                short8 av = *(const short8*)(arow + h * 64 + k0 + quad * 8);
#pragma unroll
                for (int jj = 0; jj < 4; ++jj) {
                    int c = h * 64 + jj * 16 + l15;
                    short8 bv = *(const short8*)(w1p + c * K1P + k0 + quad * 8);
                    acc1[h][jj] = __builtin_amdgcn_mfma_f32_16x16x32_bf16(av, bv, acc1[h][jj], 0, 0, 0);
                }
            }
        }
#pragma unroll
        for (int h = 0; h < H1; ++h)
#pragma unroll
            for (int jj = 0; jj < 4; ++jj) {
                int c = h * 64 + jj * 16 + l15;
                float bb = b1[c];
#pragma unroll
                for (int r = 0; r < 4; ++r)
                    hlds[wave][quad * 4 + r][c] = f2bfu(fmaxf(acc1[h][jj][r] + bb, 0.f));
            }
    }
    __syncthreads();
    if (!active) return;

    f32x4 acc2[8];
#pragma unroll
    for (int j = 0; j < 8; ++j) acc2[j] = (f32x4){0.f, 0.f, 0.f, 0.f};
    const unsigned short* a2row = &hlds[wave][l15][0] + quad * 8;
#pragma unroll
    for (int k0 = 0; k0 < C1; k0 += 32) {
        short8 av = *(const short8*)(a2row + k0);
#pragma unroll
        for (int j = 0; j < 8; ++j) {
            short8 bv = *(const short8*)(w2p + (j * 16 + l15) * C1 + k0 + quad * 8);
            acc2[j] = __builtin_amdgcn_mfma_f32_16x16x32_bf16(av, bv, acc2[j], 0, 0, 0);
        }
    }
    float ps[4] = {0.f, 0.f, 0.f, 0.f}, pd[4] = {0.f, 0.f, 0.f, 0.f};
#pragma unroll
    for (int j = 0; j < 8; ++j) {
        float as_ = atts[j * 16 + l15], ad_ = attd[j * 16 + l15];
#pragma unroll
        for (int r = 0; r < 4; ++r) {
            float v = acc2[j][r];
            h2bf[(m0 + quad * 4 + r) * C2 + j * 16 + l15] = f2bfu(v);
            ps[r] += v * as_;
            pd[r] += v * ad_;
        }
    }
#pragma unroll
    for (int r = 0; r < 4; ++r) {
#pragma unroll
        for (int o = 8; o > 0; o >>= 1) {
            ps[r] += __shfl_down(ps[r], o, 16);
            pd[r] += __shfl_down(pd[r], o, 16);
        }
        if (l15 == 0) {
            int n = m0 + quad * 4 + r;
            a_s[n] = ps[r];
            a_d[n] = pd[r];
        }
    }
}

// ---------------- layer 2 aggregate + pool: 2 nodes/wave, 8-edge unroll + tail ------
__global__ __launch_bounds__(256) void k_l2_aggpool(const int* __restrict__ degv,
                                                    const int* __restrict__ slots,
                                                    const float* __restrict__ a_s,
                                                    const float* __restrict__ a_d,
                                                    const unsigned short* __restrict__ h2bf,
                                                    const float* __restrict__ b2,
                                                    const int* __restrict__ batch,
                                                    float* __restrict__ pooled) {
    int t = threadIdx.x;
    int wave = t >> 6, lane = t & 63;
    int half = lane >> 5, hl = lane & 31;
    int d = blockIdx.x * 8 + wave * 2 + half;
    int beg = d << 6;
    int deg = degv[d];
    float ad = a_d[d];
    const uint2* rows = (const uint2*)h2bf;
    float a0 = 0.f, a1 = 0.f, a2 = 0.f, a3 = 0.f, z = 0.f;
    int i = 0;
    for (; i + 8 <= deg; i += 8) {
        int e0 = beg + i;
        int s[8]; uint2 u[8]; float ex[8];
#pragma unroll
        for (int k = 0; k < 8; ++k) s[k] = slots[e0 + k];
#pragma unroll
        for (int k = 0; k < 8; ++k) u[k] = rows[s[k] * 32 + hl];
#pragma unroll
        for (int k = 0; k < 8; ++k) ex[k] = __expf(leaky(a_s[s[k]] + ad));
#pragma unroll
        for (int k = 0; k < 8; ++k) {
            z  += ex[k];
            a0 += ex[k] * lo16(u[k].x); a1 += ex[k] * hi16(u[k].x);
            a2 += ex[k] * lo16(u[k].y); a3 += ex[k] * hi16(u[k].y);
        }
    }
    for (; i < deg; ++i) {
        int s = slots[beg + i];
        uint2 u = rows[s * 32 + hl];
        float ex = __expf(leaky(a_s[s] + ad));
        z  += ex;
        a0 += ex * lo16(u.x); a1 += ex * hi16(u.x);
        a2 += ex * lo16(u.y); a3 += ex * hi16(u.y);
    }
    float inv = 1.f / z;
    int c = hl * 4;
    float4 bv = *(const float4*)(b2 + c);
    float v0 = fmaxf(a0 * inv + bv.x, 0.f);
    float v1 = fmaxf(a1 * inv + bv.y, 0.f);
    float v2 = fmaxf(a2 * inv + bv.z, 0.f);
    float v3 = fmaxf(a3 * inv + bv.w, 0.f);
    int g = batch[d];
    int   gp = __shfl_xor(g,  32, 64);
    float w0 = __shfl_xor(v0, 32, 64);
    float w1 = __shfl_xor(v1, 32, 64);
    float w2 = __shfl_xor(v2, 32, 64);
    float w3 = __shfl_xor(v3, 32, 64);
    if (g == gp) {
        if (half == 0) {
            atomicAdd(&pooled[g * C2 + c],     v0 + w0);
            atomicAdd(&pooled[g * C2 + c + 1], v1 + w1);
            atomicAdd(&pooled[g * C2 + c + 2], v2 + w2);
            atomicAdd(&pooled[g * C2 + c + 3], v3 + w3);
        }
    } else {
        atomicAdd(&pooled[g * C2 + c],     v0);
        atomicAdd(&pooled[g * C2 + c + 1], v1);
        atomicAdd(&pooled[g * C2 + c + 2], v2);
        atomicAdd(&pooled[g * C2 + c + 3], v3);
    }
}

// ---------------- BN: cnt via binary search on sorted batch (no atomics) ----------
__global__ __launch_bounds__(512) void k_bn(const float* __restrict__ pooled,
                                            const int* __restrict__ batch,
                                            const float* __restrict__ gamma,
                                            const float* __restrict__ beta,
                                            float* __restrict__ out) {
    int c = blockIdx.x;
    int g = threadIdx.x;
    int lo = 0, hi = N_NODES;
    while (lo < hi) { int m = (lo + hi) >> 1; if (batch[m] < g) lo = m + 1; else hi = m; }
    int lo2 = lo, hi2 = N_NODES;
    while (lo2 < hi2) { int m = (lo2 + hi2) >> 1; if (batch[m] < g + 1) lo2 = m + 1; else hi2 = m; }
    float cntg = (float)(hi2 - lo);

    __shared__ float red[512];
    __shared__ float s_mu, s_var;
    float v = pooled[g * C2 + c] / fmaxf(cntg, 1.0f);
    red[g] = v;
    __syncthreads();
    for (int s = 256; s > 0; s >>= 1) {
        if (g < s) red[g] += red[g + s];
        __syncthreads();
    }
    if (g == 0) s_mu = red[0] * (1.0f / N_GRAPHS);
    __syncthreads();
    float dv = v - s_mu;
    red[g] = dv * dv;
    __syncthreads();
    for (int s = 256; s > 0; s >>= 1) {
        if (g < s) red[g] += red[g + s];
        __syncthreads();
    }
    if (g == 0) s_var = red[0] * (1.0f / N_GRAPHS);
    __syncthreads();
    out[g * C2 + c] = dv * rsqrtf(s_var + 1e-5f) * gamma[c] + beta[c];
}

extern "C" void kernel_launch(void* const* d_in, const int* in_sizes, int n_in,
                              void* d_out, int out_size, void* d_ws, size_t ws_size,
                              hipStream_t stream) {
    const float* x     = (const float*)d_in[0];
    const int*   eidx  = (const int*)d_in[1];
    const int*   batch = (const int*)d_in[2];
    const float* W1    = (const float*)d_in[3];
    const float* atts1 = (const float*)d_in[4];
    const float* attd1 = (const float*)d_in[5];
    const float* b1    = (const float*)d_in[6];
    const float* W2    = (const float*)d_in[7];
    const float* atts2 = (const float*)d_in[8];
    const float* attd2 = (const float*)d_in[9];
    const float* b2    = (const float*)d_in[10];
    const float* gamma = (const float*)d_in[11];
    const float* beta  = (const float*)d_in[12];
    float* out = (float*)d_out;
    float* ws  = (float*)d_ws;

    const int* src = eidx;
    const int* dst = eidx + N_EDGES;

    // workspace layout, float-element offsets (bf16 arrays use 2 shorts per float)
    const size_t o_xbf    = 0;           // 1,600,000
    const size_t o_xagg   = 1600000;     // 6,400,000
    const size_t o_h2bf   = 8000000;     // 3,200,000
    const size_t o_w1p    = 11200000;    // 8,192
    const size_t o_w2p    = 11208192;    // 16,384
    const size_t o_wproj  = 11224576;    // 512
    const size_t o_as1    = 11225088;    // 200,000
    const size_t o_ad1    = 11425088;    // 200,000
    const size_t o_as2    = 11625088;    // 50,000
    const size_t o_ad2    = 11675088;    // 50,000
    const size_t o_slots  = 11725088;    // 3,200,000 (50000 * 64 ints)
    // ---- contiguous zero block from here ----
    const size_t o_deg    = 14925088;    // 50,000
    const size_t o_pool   = 14975088;    // 65,536
    const size_t total    = 15040624;    // ~60 MB

    int* p_slots = (int*)(ws + o_slots);
    int* p_deg   = (int*)(ws + o_deg);
    unsigned short* p_xbf  = (unsigned short*)(ws + o_xbf);
    unsigned short* p_xagg = (unsigned short*)(ws + o_xagg);
    unsigned short* p_h2bf = (unsigned short*)(ws + o_h2bf);
    unsigned short* p_w1p  = (unsigned short*)(ws + o_w1p);
    unsigned short* p_w2p  = (unsigned short*)(ws + o_w2p);

    hipMemsetAsync(ws + o_deg, 0, (total - o_deg) * sizeof(float), stream);

    // ---- frontA: weights + att projections ----
    k_frontA<<<385, 256, 0, stream>>>(W1, W2, atts1, attd1,
                                      p_w1p, p_w2p, ws + o_wproj);
    // ---- mid: bucket build (4 edges/thread) + layer-1 logits / x cast ----
    k_mid<<<NBUILD + NATT, 256, 0, stream>>>(src, dst, p_deg, p_slots,
                                             x, ws + o_wproj, p_xbf,
                                             ws + o_as1, ws + o_ad1);

    const int nagg1 = N_NODES / 16;             // 3125: 4 waves x 4 nodes per block
    const int nagg2 = N_NODES / 8;              // 6250: 4 waves x 2 nodes per block
    const int nmfma = (N_NODES + 63) / 64;      // 782: 4 waves x 16 nodes per block

    // ---- layer 1 aggregate + fused GEMM chain ----
    k_l1_agg<<<nagg1, 256, 0, stream>>>(p_deg, p_slots, ws + o_as1, ws + o_ad1,
                                        (const uint2*)p_xbf, p_xagg);
    k_gemm12<<<nmfma, 256, 0, stream>>>(p_xagg, p_w1p, b1, p_w2p, atts2, attd2,
                                        p_h2bf, ws + o_as2, ws + o_ad2);

    // ---- layer 2 aggregate + pool ----
    k_l2_aggpool<<<nagg2, 256, 0, stream>>>(p_deg, p_slots, ws + o_as2, ws + o_ad2,
                                            p_h2bf, b2, batch, ws + o_pool);

    // ---- BN (cnt via binary search, no atomics) ----
    k_bn<<<C2, 512, 0, stream>>>(ws + o_pool, batch, gamma, beta, out);
}

// Round 21
// 319.157 us; speedup vs baseline: 1.2025x; 1.0321x over previous
//
#include <hip/hip_runtime.h>
#include <hip/hip_bf16.h>
#include <math.h>

#define N_NODES  50000
#define N_EDGES  800000
#define E_TOT    850000   // + self loops
#define N_GRAPHS 512
#define IN_CH    58
#define K1P      64       // padded K for layer-1 MFMA
#define C1       256      // HEADS1 * H = 4*64
#define H1       4
#define C2       128
#define NEG_SLOPE 0.2f
#define SLOT_CAP 64       // fixed bucket capacity; P(Poisson(17) > 63) < 1e-13
#define NBUILD   416      // ceil(850000 / (256*8)) -- 8 edges per thread
#define NATT     12500    // ceil(50000/4)

typedef __attribute__((ext_vector_type(8))) short short8;
typedef __attribute__((ext_vector_type(4))) float f32x4;

__device__ __forceinline__ float lo16(unsigned u) { return __uint_as_float(u << 16); }
__device__ __forceinline__ float hi16(unsigned u) { return __uint_as_float(u & 0xffff0000u); }
__device__ __forceinline__ float leaky(float e) { return e > 0.f ? e : NEG_SLOPE * e; }
__device__ __forceinline__ unsigned short f2bfu(float v) {
    __hip_bfloat16 b = __float2bfloat16(v);
    return *(unsigned short*)&b;
}
__device__ __forceinline__ unsigned pack2(float lo, float hi) {
    return (unsigned)f2bfu(lo) | ((unsigned)f2bfu(hi) << 16);
}

// ---- frontA: weight prep + att projections (tiny) ----
__global__ __launch_bounds__(256) void k_frontA(const float* __restrict__ W1,
                                                const float* __restrict__ W2,
                                                const float* __restrict__ atts1,
                                                const float* __restrict__ attd1,
                                                unsigned short* __restrict__ w1p,
                                                unsigned short* __restrict__ w2p,
                                                float* __restrict__ wproj) {
    int b = blockIdx.x;
    int t = threadIdx.x;
    if (b < 256) {                     // w1p[c][k] = bf16(W1[k][c]), zero-pad k>=58
        if (t < K1P) {
            float v = (t < IN_CH) ? W1[t * C1 + b] : 0.f;
            w1p[b * K1P + t] = f2bfu(v);
        }
    } else if (b < 384) {              // w2p[n][k] = bf16(W2[k][n])
        int n = b - 256;
        w2p[n * C1 + t] = f2bfu(W2[t * C2 + n]);
    } else {                           // att projections through W1
        int k = t >> 2, h = t & 3;
        float s = 0.f, dd = 0.f;
        if (k < IN_CH) {
            for (int j = 0; j < 64; ++j) {
                float wv = W1[k * C1 + h * 64 + j];
                s  += wv * atts1[h * 64 + j];
                dd += wv * attd1[h * 64 + j];
            }
        }
        wproj[t] = s;
        wproj[256 + t] = dd;
    }
}

// ---- mid: bucket build (8 edges/thread, interleaved chains) + layer-1 logits ----
__global__ __launch_bounds__(256) void k_mid(const int* __restrict__ src,
                                             const int* __restrict__ dst,
                                             int* __restrict__ deg,
                                             int* __restrict__ slots,
                                             const float* __restrict__ x,
                                             const float* __restrict__ wproj,
                                             unsigned short* __restrict__ xbf,
                                             float* __restrict__ a_s,
                                             float* __restrict__ a_d) {
    int b = blockIdx.x;
    int t = threadIdx.x;
    if (b < NBUILD) {                  // histogram + scatter, 8 independent chains
        int j0 = (b * 256 + t) * 8;
        int s[8], d[8], pos[8];
        bool v[8];
#pragma unroll
        for (int k = 0; k < 8; ++k) {
            int j = j0 + k;
            v[k] = j < E_TOT;
            if (v[k]) {
                if (j < N_EDGES) { s[k] = src[j]; d[k] = dst[j]; }
                else             { s[k] = d[k] = j - N_EDGES; }
            }
        }
#pragma unroll
        for (int k = 0; k < 8; ++k)
            if (v[k]) pos[k] = atomicAdd(&deg[d[k]], 1);
#pragma unroll
        for (int k = 0; k < 8; ++k)
            if (v[k]) slots[(d[k] << 6) + pos[k]] = s[k];
    } else {                           // layer-1 logits + x -> bf16 cast
        int n = (b - NBUILD) * 4 + (t >> 6);
        int lane = t & 63;
        float xv = (lane < IN_CH) ? x[n * IN_CH + lane] : 0.f;
        xbf[n * K1P + lane] = f2bfu(xv);
        float ps0 = xv * wproj[lane * 4 + 0], ps1 = xv * wproj[lane * 4 + 1];
        float ps2 = xv * wproj[lane * 4 + 2], ps3 = xv * wproj[lane * 4 + 3];
        float pd0 = xv * wproj[256 + lane * 4 + 0], pd1 = xv * wproj[256 + lane * 4 + 1];
        float pd2 = xv * wproj[256 + lane * 4 + 2], pd3 = xv * wproj[256 + lane * 4 + 3];
#pragma unroll
        for (int o = 32; o > 0; o >>= 1) {
            ps0 += __shfl_down(ps0, o, 64); ps1 += __shfl_down(ps1, o, 64);
            ps2 += __shfl_down(ps2, o, 64); ps3 += __shfl_down(ps3, o, 64);
            pd0 += __shfl_down(pd0, o, 64); pd1 += __shfl_down(pd1, o, 64);
            pd2 += __shfl_down(pd2, o, 64); pd3 += __shfl_down(pd3, o, 64);
        }
        if (lane == 0) {
            *(float4*)(a_s + n * 4) = make_float4(ps0, ps1, ps2, ps3);
            *(float4*)(a_d + n * 4) = make_float4(pd0, pd1, pd2, pd3);
        }
    }
}

// ---------------- layer 1 aggregate over x: 4 nodes/wave, 8-edge unroll + tail ------
__global__ __launch_bounds__(256) void k_l1_agg(const int* __restrict__ degv,
                                                const int* __restrict__ slots,
                                                const float* __restrict__ a_s,
                                                const float* __restrict__ a_d,
                                                const uint2* __restrict__ xbf,
                                                unsigned short* __restrict__ xagg) {
    int t = threadIdx.x;
    int wave = t >> 6, lane = t & 63;
    int q = lane >> 4, hl = lane & 15;
    int d = blockIdx.x * 16 + wave * 4 + q;          // 3125*16 = 50000 exact
    int beg = d << 6;
    int deg = degv[d];
    float4 ad = *(const float4*)(a_d + d * 4);
    float z0 = 0.f, z1 = 0.f, z2 = 0.f, z3 = 0.f;
    float a0[4] = {0.f, 0.f, 0.f, 0.f};
    float a1[4] = {0.f, 0.f, 0.f, 0.f};
    float a2[4] = {0.f, 0.f, 0.f, 0.f};
    float a3[4] = {0.f, 0.f, 0.f, 0.f};
    int i = 0;
    for (; i + 8 <= deg; i += 8) {
        int e0 = beg + i;
        int s[8]; uint2 u[8]; float4 as[8];
#pragma unroll
        for (int k = 0; k < 8; ++k) s[k] = slots[e0 + k];
#pragma unroll
        for (int k = 0; k < 8; ++k) u[k] = xbf[s[k] * 16 + hl];
#pragma unroll
        for (int k = 0; k < 8; ++k) as[k] = *(const float4*)(a_s + s[k] * 4);
#pragma unroll
        for (int k = 0; k < 8; ++k) {
            float e0h = __expf(leaky(as[k].x + ad.x));
            float e1h = __expf(leaky(as[k].y + ad.y));
            float e2h = __expf(leaky(as[k].z + ad.z));
            float e3h = __expf(leaky(as[k].w + ad.w));
            z0 += e0h; z1 += e1h; z2 += e2h; z3 += e3h;
            float c0 = lo16(u[k].x), c1 = hi16(u[k].x);
            float c2 = lo16(u[k].y), c3 = hi16(u[k].y);
            a0[0] += e0h * c0; a0[1] += e0h * c1; a0[2] += e0h * c2; a0[3] += e0h * c3;
            a1[0] += e1h * c0; a1[1] += e1h * c1; a1[2] += e1h * c2; a1[3] += e1h * c3;
            a2[0] += e2h * c0; a2[1] += e2h * c1; a2[2] += e2h * c2; a2[3] += e2h * c3;
            a3[0] += e3h * c0; a3[1] += e3h * c1; a3[2] += e3h * c2; a3[3] += e3h * c3;
        }
    }
    for (; i < deg; ++i) {
        int s = slots[beg + i];
        uint2 u = xbf[s * 16 + hl];
        float4 as = *(const float4*)(a_s + s * 4);
        float e0h = __expf(leaky(as.x + ad.x));
        float e1h = __expf(leaky(as.y + ad.y));
        float e2h = __expf(leaky(as.z + ad.z));
        float e3h = __expf(leaky(as.w + ad.w));
        z0 += e0h; z1 += e1h; z2 += e2h; z3 += e3h;
        float c0 = lo16(u.x), c1 = hi16(u.x);
        float c2 = lo16(u.y), c3 = hi16(u.y);
        a0[0] += e0h * c0; a0[1] += e0h * c1; a0[2] += e0h * c2; a0[3] += e0h * c3;
        a1[0] += e1h * c0; a1[1] += e1h * c1; a1[2] += e1h * c2; a1[3] += e1h * c3;
        a2[0] += e2h * c0; a2[1] += e2h * c1; a2[2] += e2h * c2; a2[3] += e2h * c3;
        a3[0] += e3h * c0; a3[1] += e3h * c1; a3[2] += e3h * c2; a3[3] += e3h * c3;
    }
    float i0 = 1.f / z0, i1 = 1.f / z1, i2 = 1.f / z2, i3 = 1.f / z3;
    uint2* xo = (uint2*)xagg;                        // 64 uint2 per row
    xo[d * 64 +  0 + hl] = make_uint2(pack2(a0[0] * i0, a0[1] * i0), pack2(a0[2] * i0, a0[3] * i0));
    xo[d * 64 + 16 + hl] = make_uint2(pack2(a1[0] * i1, a1[1] * i1), pack2(a1[2] * i1, a1[3] * i1));
    xo[d * 64 + 32 + hl] = make_uint2(pack2(a2[0] * i2, a2[1] * i2), pack2(a2[2] * i2, a2[3] * i2));
    xo[d * 64 + 48 + hl] = make_uint2(pack2(a3[0] * i3, a3[1] * i3), pack2(a3[2] * i3, a3[3] * i3));
}

// ---------------- fused layer-1+2 GEMM: xagg -> h1 (LDS) -> h2 + att logits ---------
__global__ __launch_bounds__(256) void k_gemm12(const unsigned short* __restrict__ xagg,
                                                const unsigned short* __restrict__ w1p,
                                                const float* __restrict__ b1,
                                                const unsigned short* __restrict__ w2p,
                                                const float* __restrict__ atts,
                                                const float* __restrict__ attd,
                                                unsigned short* __restrict__ h2bf,
                                                float* __restrict__ a_s,
                                                float* __restrict__ a_d) {
    __shared__ unsigned short hlds[4][16][264];   // padded row 528 B (16B-aligned)
    int t = threadIdx.x;
    int wave = t >> 6, lane = t & 63;
    int m0 = (blockIdx.x * 4 + wave) * 16;
    int l15 = lane & 15, quad = lane >> 4;
    bool active = m0 < N_NODES;

    if (active) {
        f32x4 acc1[H1][4];
#pragma unroll
        for (int h = 0; h < H1; ++h)
#pragma unroll
            for (int jj = 0; jj < 4; ++jj) acc1[h][jj] = (f32x4){0.f, 0.f, 0.f, 0.f};
        const unsigned short* arow = xagg + (m0 + l15) * C1;
#pragma unroll
        for (int h = 0; h < H1; ++h) {
#pragma unroll
            for (int k0 = 0; k0 < K1P; k0 += 32) {
                short8 av = *(const short8*)(arow + h * 64 + k0 + quad * 8);
#pragma unroll
                for (int jj = 0; jj < 4; ++jj) {
                    int c = h * 64 + jj * 16 + l15;
                    short8 bv = *(const short8*)(w1p + c * K1P + k0 + quad * 8);
                    acc1[h][jj] = __builtin_amdgcn_mfma_f32_16x16x32_bf16(av, bv, acc1[h][jj], 0, 0, 0);
                }
            }
        }
#pragma unroll
        for (int h = 0; h < H1; ++h)
#pragma unroll
            for (int jj = 0; jj < 4; ++jj) {
                int c = h * 64 + jj * 16 + l15;
                float bb = b1[c];
#pragma unroll
                for (int r = 0; r < 4; ++r)
                    hlds[wave][quad * 4 + r][c] = f2bfu(fmaxf(acc1[h][jj][r] + bb, 0.f));
            }
    }
    __syncthreads();
    if (!active) return;

    f32x4 acc2[8];
#pragma unroll
    for (int j = 0; j < 8; ++j) acc2[j] = (f32x4){0.f, 0.f, 0.f, 0.f};
    const unsigned short* a2row = &hlds[wave][l15][0] + quad * 8;
#pragma unroll
    for (int k0 = 0; k0 < C1; k0 += 32) {
        short8 av = *(const short8*)(a2row + k0);
#pragma unroll
        for (int j = 0; j < 8; ++j) {
            short8 bv = *(const short8*)(w2p + (j * 16 + l15) * C1 + k0 + quad * 8);
            acc2[j] = __builtin_amdgcn_mfma_f32_16x16x32_bf16(av, bv, acc2[j], 0, 0, 0);
        }
    }
    float ps[4] = {0.f, 0.f, 0.f, 0.f}, pd[4] = {0.f, 0.f, 0.f, 0.f};
#pragma unroll
    for (int j = 0; j < 8; ++j) {
        float as_ = atts[j * 16 + l15], ad_ = attd[j * 16 + l15];
#pragma unroll
        for (int r = 0; r < 4; ++r) {
            float v = acc2[j][r];
            h2bf[(m0 + quad * 4 + r) * C2 + j * 16 + l15] = f2bfu(v);
            ps[r] += v * as_;
            pd[r] += v * ad_;
        }
    }
#pragma unroll
    for (int r = 0; r < 4; ++r) {
#pragma unroll
        for (int o = 8; o > 0; o >>= 1) {
            ps[r] += __shfl_down(ps[r], o, 16);
            pd[r] += __shfl_down(pd[r], o, 16);
        }
        if (l15 == 0) {
            int n = m0 + quad * 4 + r;
            a_s[n] = ps[r];
            a_d[n] = pd[r];
        }
    }
}

// ---------------- layer 2 aggregate + pool: 2 nodes/wave, 8-edge unroll + tail ------
__global__ __launch_bounds__(256) void k_l2_aggpool(const int* __restrict__ degv,
                                                    const int* __restrict__ slots,
                                                    const float* __restrict__ a_s,
                                                    const float* __restrict__ a_d,
                                                    const unsigned short* __restrict__ h2bf,
                                                    const float* __restrict__ b2,
                                                    const int* __restrict__ batch,
                                                    float* __restrict__ pooled) {
    int t = threadIdx.x;
    int wave = t >> 6, lane = t & 63;
    int half = lane >> 5, hl = lane & 31;
    int d = blockIdx.x * 8 + wave * 2 + half;
    int beg = d << 6;
    int deg = degv[d];
    float ad = a_d[d];
    const uint2* rows = (const uint2*)h2bf;
    float a0 = 0.f, a1 = 0.f, a2 = 0.f, a3 = 0.f, z = 0.f;
    int i = 0;
    for (; i + 8 <= deg; i += 8) {
        int e0 = beg + i;
        int s[8]; uint2 u[8]; float ex[8];
#pragma unroll
        for (int k = 0; k < 8; ++k) s[k] = slots[e0 + k];
#pragma unroll
        for (int k = 0; k < 8; ++k) u[k] = rows[s[k] * 32 + hl];
#pragma unroll
        for (int k = 0; k < 8; ++k) ex[k] = __expf(leaky(a_s[s[k]] + ad));
#pragma unroll
        for (int k = 0; k < 8; ++k) {
            z  += ex[k];
            a0 += ex[k] * lo16(u[k].x); a1 += ex[k] * hi16(u[k].x);
            a2 += ex[k] * lo16(u[k].y); a3 += ex[k] * hi16(u[k].y);
        }
    }
    for (; i < deg; ++i) {
        int s = slots[beg + i];
        uint2 u = rows[s * 32 + hl];
        float ex = __expf(leaky(a_s[s] + ad));
        z  += ex;
        a0 += ex * lo16(u.x); a1 += ex * hi16(u.x);
        a2 += ex * lo16(u.y); a3 += ex * hi16(u.y);
    }
    float inv = 1.f / z;
    int c = hl * 4;
    float4 bv = *(const float4*)(b2 + c);
    float v0 = fmaxf(a0 * inv + bv.x, 0.f);
    float v1 = fmaxf(a1 * inv + bv.y, 0.f);
    float v2 = fmaxf(a2 * inv + bv.z, 0.f);
    float v3 = fmaxf(a3 * inv + bv.w, 0.f);
    int g = batch[d];
    int   gp = __shfl_xor(g,  32, 64);
    float w0 = __shfl_xor(v0, 32, 64);
    float w1 = __shfl_xor(v1, 32, 64);
    float w2 = __shfl_xor(v2, 32, 64);
    float w3 = __shfl_xor(v3, 32, 64);
    if (g == gp) {
        if (half == 0) {
            atomicAdd(&pooled[g * C2 + c],     v0 + w0);
            atomicAdd(&pooled[g * C2 + c + 1], v1 + w1);
            atomicAdd(&pooled[g * C2 + c + 2], v2 + w2);
            atomicAdd(&pooled[g * C2 + c + 3], v3 + w3);
        }
    } else {
        atomicAdd(&pooled[g * C2 + c],     v0);
        atomicAdd(&pooled[g * C2 + c + 1], v1);
        atomicAdd(&pooled[g * C2 + c + 2], v2);
        atomicAdd(&pooled[g * C2 + c + 3], v3);
    }
}

// ---------------- BN: cnt via binary search on sorted batch (no atomics) ----------
__global__ __launch_bounds__(512) void k_bn(const float* __restrict__ pooled,
                                            const int* __restrict__ batch,
                                            const float* __restrict__ gamma,
                                            const float* __restrict__ beta,
                                            float* __restrict__ out) {
    int c = blockIdx.x;
    int g = threadIdx.x;
    int lo = 0, hi = N_NODES;
    while (lo < hi) { int m = (lo + hi) >> 1; if (batch[m] < g) lo = m + 1; else hi = m; }
    int lo2 = lo, hi2 = N_NODES;
    while (lo2 < hi2) { int m = (lo2 + hi2) >> 1; if (batch[m] < g + 1) lo2 = m + 1; else hi2 = m; }
    float cntg = (float)(hi2 - lo);

    __shared__ float red[512];
    __shared__ float s_mu, s_var;
    float v = pooled[g * C2 + c] / fmaxf(cntg, 1.0f);
    red[g] = v;
    __syncthreads();
    for (int s = 256; s > 0; s >>= 1) {
        if (g < s) red[g] += red[g + s];
        __syncthreads();
    }
    if (g == 0) s_mu = red[0] * (1.0f / N_GRAPHS);
    __syncthreads();
    float dv = v - s_mu;
    red[g] = dv * dv;
    __syncthreads();
    for (int s = 256; s > 0; s >>= 1) {
        if (g < s) red[g] += red[g + s];
        __syncthreads();
    }
    if (g == 0) s_var = red[0] * (1.0f / N_GRAPHS);
    __syncthreads();
    out[g * C2 + c] = dv * rsqrtf(s_var + 1e-5f) * gamma[c] + beta[c];
}

extern "C" void kernel_launch(void* const* d_in, const int* in_sizes, int n_in,
                              void* d_out, int out_size, void* d_ws, size_t ws_size,
                              hipStream_t stream) {
    const float* x     = (const float*)d_in[0];
    const int*   eidx  = (const int*)d_in[1];
    const int*   batch = (const int*)d_in[2];
    const float* W1    = (const float*)d_in[3];
    const float* atts1 = (const float*)d_in[4];
    const float* attd1 = (const float*)d_in[5];
    const float* b1    = (const float*)d_in[6];
    const float* W2    = (const float*)d_in[7];
    const float* atts2 = (const float*)d_in[8];
    const float* attd2 = (const float*)d_in[9];
    const float* b2    = (const float*)d_in[10];
    const float* gamma = (const float*)d_in[11];
    const float* beta  = (const float*)d_in[12];
    float* out = (float*)d_out;
    float* ws  = (float*)d_ws;

    const int* src = eidx;
    const int* dst = eidx + N_EDGES;

    // workspace layout, float-element offsets (bf16 arrays use 2 shorts per float)
    const size_t o_xbf    = 0;           // 1,600,000
    const size_t o_xagg   = 1600000;     // 6,400,000
    const size_t o_h2bf   = 8000000;     // 3,200,000
    const size_t o_w1p    = 11200000;    // 8,192
    const size_t o_w2p    = 11208192;    // 16,384
    const size_t o_wproj  = 11224576;    // 512
    const size_t o_as1    = 11225088;    // 200,000
    const size_t o_ad1    = 11425088;    // 200,000
    const size_t o_as2    = 11625088;    // 50,000
    const size_t o_ad2    = 11675088;    // 50,000
    const size_t o_slots  = 11725088;    // 3,200,000 (50000 * 64 ints)
    // ---- contiguous zero block from here ----
    const size_t o_deg    = 14925088;    // 50,000
    const size_t o_pool   = 14975088;    // 65,536
    const size_t total    = 15040624;    // ~60 MB

    int* p_slots = (int*)(ws + o_slots);
    int* p_deg   = (int*)(ws + o_deg);
    unsigned short* p_xbf  = (unsigned short*)(ws + o_xbf);
    unsigned short* p_xagg = (unsigned short*)(ws + o_xagg);
    unsigned short* p_h2bf = (unsigned short*)(ws + o_h2bf);
    unsigned short* p_w1p  = (unsigned short*)(ws + o_w1p);
    unsigned short* p_w2p  = (unsigned short*)(ws + o_w2p);

    hipMemsetAsync(ws + o_deg, 0, (total - o_deg) * sizeof(float), stream);

    // ---- frontA: weights + att projections ----
    k_frontA<<<385, 256, 0, stream>>>(W1, W2, atts1, attd1,
                                      p_w1p, p_w2p, ws + o_wproj);
    // ---- mid: bucket build (8 edges/thread) + layer-1 logits / x cast ----
    k_mid<<<NBUILD + NATT, 256, 0, stream>>>(src, dst, p_deg, p_slots,
                                             x, ws + o_wproj, p_xbf,
                                             ws + o_as1, ws + o_ad1);

    const int nagg1 = N_NODES / 16;             // 3125: 4 waves x 4 nodes per block
    const int nagg2 = N_NODES / 8;              // 6250: 4 waves x 2 nodes per block
    const int nmfma = (N_NODES + 63) / 64;      // 782: 4 waves x 16 nodes per block

    // ---- layer 1 aggregate + fused GEMM chain ----
    k_l1_agg<<<nagg1, 256, 0, stream>>>(p_deg, p_slots, ws + o_as1, ws + o_ad1,
                                        (const uint2*)p_xbf, p_xagg);
    k_gemm12<<<nmfma, 256, 0, stream>>>(p_xagg, p_w1p, b1, p_w2p, atts2, attd2,
                                        p_h2bf, ws + o_as2, ws + o_ad2);

    // ---- layer 2 aggregate + pool ----
    k_l2_aggpool<<<nagg2, 256, 0, stream>>>(p_deg, p_slots, ws + o_as2, ws + o_ad2,
                                            p_h2bf, b2, batch, ws + o_pool);

    // ---- BN (cnt via binary search, no atomics) ----
    k_bn<<<C2, 512, 0, stream>>>(ws + o_pool, batch, gamma, beta, out);
}

// Round 22
// 310.734 us; speedup vs baseline: 1.2351x; 1.0271x over previous
//
#include <hip/hip_runtime.h>
#include <hip/hip_bf16.h>
#include <math.h>

#define N_NODES  50000
#define N_EDGES  800000
#define E_TOT    850000   // + self loops
#define N_GRAPHS 512
#define IN_CH    58
#define K1P      64       // padded K for layer-1 MFMA
#define C1       256      // HEADS1 * H = 4*64
#define H1       4
#define C2       128
#define NEG_SLOPE 0.2f
#define SLOT_CAP 64       // fixed bucket capacity; P(Poisson(17) > 63) < 1e-13
#define NBUILD   208      // ceil(850000 / (256*16)) -- 16 edges per thread
#define NATT     12500    // ceil(50000/4)

typedef __attribute__((ext_vector_type(8))) short short8;
typedef __attribute__((ext_vector_type(4))) float f32x4;

__device__ __forceinline__ float lo16(unsigned u) { return __uint_as_float(u << 16); }
__device__ __forceinline__ float hi16(unsigned u) { return __uint_as_float(u & 0xffff0000u); }
__device__ __forceinline__ float leaky(float e) { return e > 0.f ? e : NEG_SLOPE * e; }
__device__ __forceinline__ unsigned short f2bfu(float v) {
    __hip_bfloat16 b = __float2bfloat16(v);
    return *(unsigned short*)&b;
}
__device__ __forceinline__ unsigned pack2(float lo, float hi) {
    return (unsigned)f2bfu(lo) | ((unsigned)f2bfu(hi) << 16);
}

// ---- frontA: weight prep + att projections (tiny) ----
__global__ __launch_bounds__(256) void k_frontA(const float* __restrict__ W1,
                                                const float* __restrict__ W2,
                                                const float* __restrict__ atts1,
                                                const float* __restrict__ attd1,
                                                unsigned short* __restrict__ w1p,
                                                unsigned short* __restrict__ w2p,
                                                float* __restrict__ wproj) {
    int b = blockIdx.x;
    int t = threadIdx.x;
    if (b < 256) {                     // w1p[c][k] = bf16(W1[k][c]), zero-pad k>=58
        if (t < K1P) {
            float v = (t < IN_CH) ? W1[t * C1 + b] : 0.f;
            w1p[b * K1P + t] = f2bfu(v);
        }
    } else if (b < 384) {              // w2p[n][k] = bf16(W2[k][n])
        int n = b - 256;
        w2p[n * C1 + t] = f2bfu(W2[t * C2 + n]);
    } else {                           // att projections through W1
        int k = t >> 2, h = t & 3;
        float s = 0.f, dd = 0.f;
        if (k < IN_CH) {
            for (int j = 0; j < 64; ++j) {
                float wv = W1[k * C1 + h * 64 + j];
                s  += wv * atts1[h * 64 + j];
                dd += wv * attd1[h * 64 + j];
            }
        }
        wproj[t] = s;
        wproj[256 + t] = dd;
    }
}

// ---- mid: bucket build (16 edges/thread, interleaved chains) + layer-1 logits ----
__global__ __launch_bounds__(256) void k_mid(const int* __restrict__ src,
                                             const int* __restrict__ dst,
                                             int* __restrict__ deg,
                                             int* __restrict__ slots,
                                             const float* __restrict__ x,
                                             const float* __restrict__ wproj,
                                             unsigned short* __restrict__ xbf,
                                             float* __restrict__ a_s,
                                             float* __restrict__ a_d) {
    int b = blockIdx.x;
    int t = threadIdx.x;
    if (b < NBUILD) {                  // histogram + scatter, 16 independent chains
        int j0 = (b * 256 + t) * 16;
        int s[16], d[16], pos[16];
        bool v[16];
#pragma unroll
        for (int k = 0; k < 16; ++k) {
            int j = j0 + k;
            v[k] = j < E_TOT;
            if (v[k]) {
                if (j < N_EDGES) { s[k] = src[j]; d[k] = dst[j]; }
                else             { s[k] = d[k] = j - N_EDGES; }
            }
        }
#pragma unroll
        for (int k = 0; k < 16; ++k)
            if (v[k]) pos[k] = atomicAdd(&deg[d[k]], 1);
#pragma unroll
        for (int k = 0; k < 16; ++k)
            if (v[k]) slots[(d[k] << 6) + pos[k]] = s[k];
    } else {                           // layer-1 logits + x -> bf16 cast
        int n = (b - NBUILD) * 4 + (t >> 6);
        int lane = t & 63;
        float xv = (lane < IN_CH) ? x[n * IN_CH + lane] : 0.f;
        xbf[n * K1P + lane] = f2bfu(xv);
        float ps0 = xv * wproj[lane * 4 + 0], ps1 = xv * wproj[lane * 4 + 1];
        float ps2 = xv * wproj[lane * 4 + 2], ps3 = xv * wproj[lane * 4 + 3];
        float pd0 = xv * wproj[256 + lane * 4 + 0], pd1 = xv * wproj[256 + lane * 4 + 1];
        float pd2 = xv * wproj[256 + lane * 4 + 2], pd3 = xv * wproj[256 + lane * 4 + 3];
#pragma unroll
        for (int o = 32; o > 0; o >>= 1) {
            ps0 += __shfl_down(ps0, o, 64); ps1 += __shfl_down(ps1, o, 64);
            ps2 += __shfl_down(ps2, o, 64); ps3 += __shfl_down(ps3, o, 64);
            pd0 += __shfl_down(pd0, o, 64); pd1 += __shfl_down(pd1, o, 64);
            pd2 += __shfl_down(pd2, o, 64); pd3 += __shfl_down(pd3, o, 64);
        }
        if (lane == 0) {
            *(float4*)(a_s + n * 4) = make_float4(ps0, ps1, ps2, ps3);
            *(float4*)(a_d + n * 4) = make_float4(pd0, pd1, pd2, pd3);
        }
    }
}

// ---------------- layer 1 aggregate over x: 4 nodes/wave, 8-edge unroll + tail ------
__global__ __launch_bounds__(256) void k_l1_agg(const int* __restrict__ degv,
                                                const int* __restrict__ slots,
                                                const float* __restrict__ a_s,
                                                const float* __restrict__ a_d,
                                                const uint2* __restrict__ xbf,
                                                unsigned short* __restrict__ xagg) {
    int t = threadIdx.x;
    int wave = t >> 6, lane = t & 63;
    int q = lane >> 4, hl = lane & 15;
    int d = blockIdx.x * 16 + wave * 4 + q;          // 3125*16 = 50000 exact
    int beg = d << 6;
    int deg = degv[d];
    float4 ad = *(const float4*)(a_d + d * 4);
    float z0 = 0.f, z1 = 0.f, z2 = 0.f, z3 = 0.f;
    float a0[4] = {0.f, 0.f, 0.f, 0.f};
    float a1[4] = {0.f, 0.f, 0.f, 0.f};
    float a2[4] = {0.f, 0.f, 0.f, 0.f};
    float a3[4] = {0.f, 0.f, 0.f, 0.f};
    int i = 0;
    for (; i + 8 <= deg; i += 8) {
        int e0 = beg + i;
        int s[8]; uint2 u[8]; float4 as[8];
#pragma unroll
        for (int k = 0; k < 8; ++k) s[k] = slots[e0 + k];
#pragma unroll
        for (int k = 0; k < 8; ++k) u[k] = xbf[s[k] * 16 + hl];
#pragma unroll
        for (int k = 0; k < 8; ++k) as[k] = *(const float4*)(a_s + s[k] * 4);
#pragma unroll
        for (int k = 0; k < 8; ++k) {
            float e0h = __expf(leaky(as[k].x + ad.x));
            float e1h = __expf(leaky(as[k].y + ad.y));
            float e2h = __expf(leaky(as[k].z + ad.z));
            float e3h = __expf(leaky(as[k].w + ad.w));
            z0 += e0h; z1 += e1h; z2 += e2h; z3 += e3h;
            float c0 = lo16(u[k].x), c1 = hi16(u[k].x);
            float c2 = lo16(u[k].y), c3 = hi16(u[k].y);
            a0[0] += e0h * c0; a0[1] += e0h * c1; a0[2] += e0h * c2; a0[3] += e0h * c3;
            a1[0] += e1h * c0; a1[1] += e1h * c1; a1[2] += e1h * c2; a1[3] += e1h * c3;
            a2[0] += e2h * c0; a2[1] += e2h * c1; a2[2] += e2h * c2; a2[3] += e2h * c3;
            a3[0] += e3h * c0; a3[1] += e3h * c1; a3[2] += e3h * c2; a3[3] += e3h * c3;
        }
    }
    for (; i < deg; ++i) {
        int s = slots[beg + i];
        uint2 u = xbf[s * 16 + hl];
        float4 as = *(const float4*)(a_s + s * 4);
        float e0h = __expf(leaky(as.x + ad.x));
        float e1h = __expf(leaky(as.y + ad.y));
        float e2h = __expf(leaky(as.z + ad.z));
        float e3h = __expf(leaky(as.w + ad.w));
        z0 += e0h; z1 += e1h; z2 += e2h; z3 += e3h;
        float c0 = lo16(u.x), c1 = hi16(u.x);
        float c2 = lo16(u.y), c3 = hi16(u.y);
        a0[0] += e0h * c0; a0[1] += e0h * c1; a0[2] += e0h * c2; a0[3] += e0h * c3;
        a1[0] += e1h * c0; a1[1] += e1h * c1; a1[2] += e1h * c2; a1[3] += e1h * c3;
        a2[0] += e2h * c0; a2[1] += e2h * c1; a2[2] += e2h * c2; a2[3] += e2h * c3;
        a3[0] += e3h * c0; a3[1] += e3h * c1; a3[2] += e3h * c2; a3[3] += e3h * c3;
    }
    float i0 = 1.f / z0, i1 = 1.f / z1, i2 = 1.f / z2, i3 = 1.f / z3;
    uint2* xo = (uint2*)xagg;                        // 64 uint2 per row
    xo[d * 64 +  0 + hl] = make_uint2(pack2(a0[0] * i0, a0[1] * i0), pack2(a0[2] * i0, a0[3] * i0));
    xo[d * 64 + 16 + hl] = make_uint2(pack2(a1[0] * i1, a1[1] * i1), pack2(a1[2] * i1, a1[3] * i1));
    xo[d * 64 + 32 + hl] = make_uint2(pack2(a2[0] * i2, a2[1] * i2), pack2(a2[2] * i2, a2[3] * i2));
    xo[d * 64 + 48 + hl] = make_uint2(pack2(a3[0] * i3, a3[1] * i3), pack2(a3[2] * i3, a3[3] * i3));
}

// ---------------- fused layer-1+2 GEMM: xagg -> h1 (LDS) -> h2 + att logits ---------
__global__ __launch_bounds__(256) void k_gemm12(const unsigned short* __restrict__ xagg,
                                                const unsigned short* __restrict__ w1p,
                                                const float* __restrict__ b1,
                                                const unsigned short* __restrict__ w2p,
                                                const float* __restrict__ atts,
                                                const float* __restrict__ attd,
                                                unsigned short* __restrict__ h2bf,
                                                float* __restrict__ a_s,
                                                float* __restrict__ a_d) {
    __shared__ unsigned short hlds[4][16][264];   // padded row 528 B (16B-aligned)
    int t = threadIdx.x;
    int wave = t >> 6, lane = t & 63;
    int m0 = (blockIdx.x * 4 + wave) * 16;
    int l15 = lane & 15, quad = lane >> 4;
    bool active = m0 < N_NODES;

    if (active) {
        f32x4 acc1[H1][4];
#pragma unroll
        for (int h = 0; h < H1; ++h)
#pragma unroll
            for (int jj = 0; jj < 4; ++jj) acc1[h][jj] = (f32x4){0.f, 0.f, 0.f, 0.f};
        const unsigned short* arow = xagg + (m0 + l15) * C1;
#pragma unroll
        for (int h = 0; h < H1; ++h) {
#pragma unroll
            for (int k0 = 0; k0 < K1P; k0 += 32) {
                short8 av = *(const short8*)(arow + h * 64 + k0 + quad * 8);
#pragma unroll
                for (int jj = 0; jj < 4; ++jj) {
                    int c = h * 64 + jj * 16 + l15;
                    short8 bv = *(const short8*)(w1p + c * K1P + k0 + quad * 8);
                    acc1[h][jj] = __builtin_amdgcn_mfma_f32_16x16x32_bf16(av, bv, acc1[h][jj], 0, 0, 0);
                }
            }
        }
#pragma unroll
        for (int h = 0; h < H1; ++h)
#pragma unroll
            for (int jj = 0; jj < 4; ++jj) {
                int c = h * 64 + jj * 16 + l15;
                float bb = b1[c];
#pragma unroll
                for (int r = 0; r < 4; ++r)
                    hlds[wave][quad * 4 + r][c] = f2bfu(fmaxf(acc1[h][jj][r] + bb, 0.f));
            }
    }
    __syncthreads();
    if (!active) return;

    f32x4 acc2[8];
#pragma unroll
    for (int j = 0; j < 8; ++j) acc2[j] = (f32x4){0.f, 0.f, 0.f, 0.f};
    const unsigned short* a2row = &hlds[wave][l15][0] + quad * 8;
#pragma unroll
    for (int k0 = 0; k0 < C1; k0 += 32) {
        short8 av = *(const short8*)(a2row + k0);
#pragma unroll
        for (int j = 0; j < 8; ++j) {
            short8 bv = *(const short8*)(w2p + (j * 16 + l15) * C1 + k0 + quad * 8);
            acc2[j] = __builtin_amdgcn_mfma_f32_16x16x32_bf16(av, bv, acc2[j], 0, 0, 0);
        }
    }
    float ps[4] = {0.f, 0.f, 0.f, 0.f}, pd[4] = {0.f, 0.f, 0.f, 0.f};
#pragma unroll
    for (int j = 0; j < 8; ++j) {
        float as_ = atts[j * 16 + l15], ad_ = attd[j * 16 + l15];
#pragma unroll
        for (int r = 0; r < 4; ++r) {
            float v = acc2[j][r];
            h2bf[(m0 + quad * 4 + r) * C2 + j * 16 + l15] = f2bfu(v);
            ps[r] += v * as_;
            pd[r] += v * ad_;
        }
    }
#pragma unroll
    for (int r = 0; r < 4; ++r) {
#pragma unroll
        for (int o = 8; o > 0; o >>= 1) {
            ps[r] += __shfl_down(ps[r], o, 16);
            pd[r] += __shfl_down(pd[r], o, 16);
        }
        if (l15 == 0) {
            int n = m0 + quad * 4 + r;
            a_s[n] = ps[r];
            a_d[n] = pd[r];
        }
    }
}

// ---------------- layer 2 aggregate + pool: 2 nodes/wave, 8-edge unroll + tail ------
__global__ __launch_bounds__(256) void k_l2_aggpool(const int* __restrict__ degv,
                                                    const int* __restrict__ slots,
                                                    const float* __restrict__ a_s,
                                                    const float* __restrict__ a_d,
                                                    const unsigned short* __restrict__ h2bf,
                                                    const float* __restrict__ b2,
                                                    const int* __restrict__ batch,
                                                    float* __restrict__ pooled) {
    int t = threadIdx.x;
    int wave = t >> 6, lane = t & 63;
    int half = lane >> 5, hl = lane & 31;
    int d = blockIdx.x * 8 + wave * 2 + half;
    int beg = d << 6;
    int deg = degv[d];
    float ad = a_d[d];
    const uint2* rows = (const uint2*)h2bf;
    float a0 = 0.f, a1 = 0.f, a2 = 0.f, a3 = 0.f, z = 0.f;
    int i = 0;
    for (; i + 8 <= deg; i += 8) {
        int e0 = beg + i;
        int s[8]; uint2 u[8]; float ex[8];
#pragma unroll
        for (int k = 0; k < 8; ++k) s[k] = slots[e0 + k];
#pragma unroll
        for (int k = 0; k < 8; ++k) u[k] = rows[s[k] * 32 + hl];
#pragma unroll
        for (int k = 0; k < 8; ++k) ex[k] = __expf(leaky(a_s[s[k]] + ad));
#pragma unroll
        for (int k = 0; k < 8; ++k) {
            z  += ex[k];
            a0 += ex[k] * lo16(u[k].x); a1 += ex[k] * hi16(u[k].x);
            a2 += ex[k] * lo16(u[k].y); a3 += ex[k] * hi16(u[k].y);
        }
    }
    for (; i < deg; ++i) {
        int s = slots[beg + i];
        uint2 u = rows[s * 32 + hl];
        float ex = __expf(leaky(a_s[s] + ad));
        z  += ex;
        a0 += ex * lo16(u.x); a1 += ex * hi16(u.x);
        a2 += ex * lo16(u.y); a3 += ex * hi16(u.y);
    }
    float inv = 1.f / z;
    int c = hl * 4;
    float4 bv = *(const float4*)(b2 + c);
    float v0 = fmaxf(a0 * inv + bv.x, 0.f);
    float v1 = fmaxf(a1 * inv + bv.y, 0.f);
    float v2 = fmaxf(a2 * inv + bv.z, 0.f);
    float v3 = fmaxf(a3 * inv + bv.w, 0.f);
    int g = batch[d];
    int   gp = __shfl_xor(g,  32, 64);
    float w0 = __shfl_xor(v0, 32, 64);
    float w1 = __shfl_xor(v1, 32, 64);
    float w2 = __shfl_xor(v2, 32, 64);
    float w3 = __shfl_xor(v3, 32, 64);
    if (g == gp) {
        if (half == 0) {
            atomicAdd(&pooled[g * C2 + c],     v0 + w0);
            atomicAdd(&pooled[g * C2 + c + 1], v1 + w1);
            atomicAdd(&pooled[g * C2 + c + 2], v2 + w2);
            atomicAdd(&pooled[g * C2 + c + 3], v3 + w3);
        }
    } else {
        atomicAdd(&pooled[g * C2 + c],     v0);
        atomicAdd(&pooled[g * C2 + c + 1], v1);
        atomicAdd(&pooled[g * C2 + c + 2], v2);
        atomicAdd(&pooled[g * C2 + c + 3], v3);
    }
}

// ---------------- BN: cnt via binary search on sorted batch (no atomics) ----------
__global__ __launch_bounds__(512) void k_bn(const float* __restrict__ pooled,
                                            const int* __restrict__ batch,
                                            const float* __restrict__ gamma,
                                            const float* __restrict__ beta,
                                            float* __restrict__ out) {
    int c = blockIdx.x;
    int g = threadIdx.x;
    int lo = 0, hi = N_NODES;
    while (lo < hi) { int m = (lo + hi) >> 1; if (batch[m] < g) lo = m + 1; else hi = m; }
    int lo2 = lo, hi2 = N_NODES;
    while (lo2 < hi2) { int m = (lo2 + hi2) >> 1; if (batch[m] < g + 1) lo2 = m + 1; else hi2 = m; }
    float cntg = (float)(hi2 - lo);

    __shared__ float red[512];
    __shared__ float s_mu, s_var;
    float v = pooled[g * C2 + c] / fmaxf(cntg, 1.0f);
    red[g] = v;
    __syncthreads();
    for (int s = 256; s > 0; s >>= 1) {
        if (g < s) red[g] += red[g + s];
        __syncthreads();
    }
    if (g == 0) s_mu = red[0] * (1.0f / N_GRAPHS);
    __syncthreads();
    float dv = v - s_mu;
    red[g] = dv * dv;
    __syncthreads();
    for (int s = 256; s > 0; s >>= 1) {
        if (g < s) red[g] += red[g + s];
        __syncthreads();
    }
    if (g == 0) s_var = red[0] * (1.0f / N_GRAPHS);
    __syncthreads();
    out[g * C2 + c] = dv * rsqrtf(s_var + 1e-5f) * gamma[c] + beta[c];
}

extern "C" void kernel_launch(void* const* d_in, const int* in_sizes, int n_in,
                              void* d_out, int out_size, void* d_ws, size_t ws_size,
                              hipStream_t stream) {
    const float* x     = (const float*)d_in[0];
    const int*   eidx  = (const int*)d_in[1];
    const int*   batch = (const int*)d_in[2];
    const float* W1    = (const float*)d_in[3];
    const float* atts1 = (const float*)d_in[4];
    const float* attd1 = (const float*)d_in[5];
    const float* b1    = (const float*)d_in[6];
    const float* W2    = (const float*)d_in[7];
    const float* atts2 = (const float*)d_in[8];
    const float* attd2 = (const float*)d_in[9];
    const float* b2    = (const float*)d_in[10];
    const float* gamma = (const float*)d_in[11];
    const float* beta  = (const float*)d_in[12];
    float* out = (float*)d_out;
    float* ws  = (float*)d_ws;

    const int* src = eidx;
    const int* dst = eidx + N_EDGES;

    // workspace layout, float-element offsets (bf16 arrays use 2 shorts per float)
    const size_t o_xbf    = 0;           // 1,600,000
    const size_t o_xagg   = 1600000;     // 6,400,000
    const size_t o_h2bf   = 8000000;     // 3,200,000
    const size_t o_w1p    = 11200000;    // 8,192
    const size_t o_w2p    = 11208192;    // 16,384
    const size_t o_wproj  = 11224576;    // 512
    const size_t o_as1    = 11225088;    // 200,000
    const size_t o_ad1    = 11425088;    // 200,000
    const size_t o_as2    = 11625088;    // 50,000
    const size_t o_ad2    = 11675088;    // 50,000
    const size_t o_slots  = 11725088;    // 3,200,000 (50000 * 64 ints)
    // ---- contiguous zero block from here ----
    const size_t o_deg    = 14925088;    // 50,000
    const size_t o_pool   = 14975088;    // 65,536
    const size_t total    = 15040624;    // ~60 MB

    int* p_slots = (int*)(ws + o_slots);
    int* p_deg   = (int*)(ws + o_deg);
    unsigned short* p_xbf  = (unsigned short*)(ws + o_xbf);
    unsigned short* p_xagg = (unsigned short*)(ws + o_xagg);
    unsigned short* p_h2bf = (unsigned short*)(ws + o_h2bf);
    unsigned short* p_w1p  = (unsigned short*)(ws + o_w1p);
    unsigned short* p_w2p  = (unsigned short*)(ws + o_w2p);

    hipMemsetAsync(ws + o_deg, 0, (total - o_deg) * sizeof(float), stream);

    // ---- frontA: weights + att projections ----
    k_frontA<<<385, 256, 0, stream>>>(W1, W2, atts1, attd1,
                                      p_w1p, p_w2p, ws + o_wproj);
    // ---- mid: bucket build (16 edges/thread) + layer-1 logits / x cast ----
    k_mid<<<NBUILD + NATT, 256, 0, stream>>>(src, dst, p_deg, p_slots,
                                             x, ws + o_wproj, p_xbf,
                                             ws + o_as1, ws + o_ad1);

    const int nagg1 = N_NODES / 16;             // 3125: 4 waves x 4 nodes per block
    const int nagg2 = N_NODES / 8;              // 6250: 4 waves x 2 nodes per block
    const int nmfma = (N_NODES + 63) / 64;      // 782: 4 waves x 16 nodes per block

    // ---- layer 1 aggregate + fused GEMM chain ----
    k_l1_agg<<<nagg1, 256, 0, stream>>>(p_deg, p_slots, ws + o_as1, ws + o_ad1,
                                        (const uint2*)p_xbf, p_xagg);
    k_gemm12<<<nmfma, 256, 0, stream>>>(p_xagg, p_w1p, b1, p_w2p, atts2, attd2,
                                        p_h2bf, ws + o_as2, ws + o_ad2);

    // ---- layer 2 aggregate + pool ----
    k_l2_aggpool<<<nagg2, 256, 0, stream>>>(p_deg, p_slots, ws + o_as2, ws + o_ad2,
                                            p_h2bf, b2, batch, ws + o_pool);

    // ---- BN (cnt via binary search, no atomics) ----
    k_bn<<<C2, 512, 0, stream>>>(ws + o_pool, batch, gamma, beta, out);
}